// Round 3
// baseline (256.018 us; speedup 1.0000x reference)
//
#include <hip/hip_runtime.h>
#include <math.h>

#define BB 512
#define SS 16384
#define TPIF 6.28318530717958647692f

// pad so strides {1(contig-16), 4, 64, 1024} across lanes are ~conflict-free (b32)
#define PAD32(i) ((i) + ((i) >> 5) + ((i) >> 10))
#define NPAD 16912   // PAD32(16383)=16909 < 16912

#define K16C0 1.0f
#define K16C1 0.92387953251128674f
#define K16C2 0.70710678118654752f
#define K16C3 0.38268343236508977f
#define K16S0 0.0f
#define K16S1 0.38268343236508977f
#define K16S2 0.70710678118654752f
#define K16S3 0.92387953251128674f

// base-4 digit reversal of 14-bit index (7 digits)
__device__ __forceinline__ int digrev4(int n) {
    unsigned x = __brev((unsigned)n) >> (32 - 14);
    return (int)(((x & 0x1555u) << 1) | ((x >> 1) & 0x1555u));
}

// ---------------------------------------------------------------------------
// Fused DIF pair: stage stride 4Q (block 16Q) then stride Q (block 4Q).
// Thread holds 16 elements z[m] at positions base + m*Q, base = 16*Q*G + p.
// ---------------------------------------------------------------------------
template <int SGN, int Q>
__device__ __forceinline__ void dif_pair(float* zr, float* zi, int p) {
    const float sg = (float)SGN;
    const float kc[4] = {K16C0, K16C1, K16C2, K16C3};
    const float ks[4] = {K16S0, K16S1, K16S2, K16S3};
    {   // stage 1: stride 4 in m, twiddle W_{16Q}^{r*(p+cQ)} on outputs
        const float arev = sg * (float)p * (1.0f / (16.0f * (float)Q));
        const float cb = __builtin_amdgcn_cosf(arev);
        const float sb = __builtin_amdgcn_sinf(arev);
        #pragma unroll
        for (int c = 0; c < 4; ++c) {
            float t0r = zr[c] + zr[c+8],   t0i = zi[c] + zi[c+8];
            float t1r = zr[c] - zr[c+8],   t1i = zi[c] - zi[c+8];
            float t2r = zr[c+4] + zr[c+12], t2i = zi[c+4] + zi[c+12];
            float t3r = zr[c+4] - zr[c+12], t3i = zi[c+4] - zi[c+12];
            float b0r = t0r + t2r, b0i = t0i + t2i;
            float b2r = t0r - t2r, b2i = t0i - t2i;
            float b1r = t1r - sg * t3i, b1i = t1i + sg * t3r;
            float b3r = t1r + sg * t3i, b3i = t1i - sg * t3r;
            float kcc = kc[c], kss = sg * ks[c];
            float w1r = cb * kcc - sb * kss, w1i = sb * kcc + cb * kss;
            float w2r = w1r * w1r - w1i * w1i, w2i = 2.0f * w1r * w1i;
            float w3r = w1r * w2r - w1i * w2i, w3i = w1r * w2i + w1i * w2r;
            zr[c]    = b0r;                   zi[c]    = b0i;
            zr[c+4]  = b1r * w1r - b1i * w1i; zi[c+4]  = b1r * w1i + b1i * w1r;
            zr[c+8]  = b2r * w2r - b2i * w2i; zi[c+8]  = b2r * w2i + b2i * w2r;
            zr[c+12] = b3r * w3r - b3i * w3i; zi[c+12] = b3r * w3i + b3i * w3r;
        }
    }
    {   // stage 2: stride 1 in m, twiddle W_{4Q}^{r*p} on outputs
        const float arev = sg * (float)p * (1.0f / (4.0f * (float)Q));
        const float cb = __builtin_amdgcn_cosf(arev);
        const float sb = __builtin_amdgcn_sinf(arev);
        const float w2r = cb * cb - sb * sb, w2i = 2.0f * cb * sb;
        const float w3r = cb * w2r - sb * w2i, w3i = cb * w2i + sb * w2r;
        #pragma unroll
        for (int r = 0; r < 4; ++r) {
            const int b = 4 * r;
            float t0r = zr[b] + zr[b+2],   t0i = zi[b] + zi[b+2];
            float t1r = zr[b] - zr[b+2],   t1i = zi[b] - zi[b+2];
            float t2r = zr[b+1] + zr[b+3], t2i = zi[b+1] + zi[b+3];
            float t3r = zr[b+1] - zr[b+3], t3i = zi[b+1] - zi[b+3];
            float b0r = t0r + t2r, b0i = t0i + t2i;
            float b2r = t0r - t2r, b2i = t0i - t2i;
            float b1r = t1r - sg * t3i, b1i = t1i + sg * t3r;
            float b3r = t1r + sg * t3i, b3i = t1i - sg * t3r;
            zr[b]   = b0r;                  zi[b]   = b0i;
            zr[b+1] = b1r * cb - b1i * sb;  zi[b+1] = b1r * sb + b1i * cb;
            zr[b+2] = b2r * w2r - b2i * w2i; zi[b+2] = b2r * w2i + b2i * w2r;
            zr[b+3] = b3r * w3r - b3i * w3i; zi[b+3] = b3r * w3i + b3i * w3r;
        }
    }
}

// ---------------------------------------------------------------------------
// Fused DIT pair: stage stride Q (block 4Q) then stride 4Q (block 16Q).
// Twiddles on INPUTS.
// ---------------------------------------------------------------------------
template <int SGN, int Q>
__device__ __forceinline__ void dit_pair(float* zr, float* zi, int p) {
    const float sg = (float)SGN;
    const float kc[4] = {K16C0, K16C1, K16C2, K16C3};
    const float ks[4] = {K16S0, K16S1, K16S2, K16S3};
    {   // stage 1: stride 1 in m, twiddle W_{4Q}^{j*p} on inputs
        const float arev = sg * (float)p * (1.0f / (4.0f * (float)Q));
        const float cb = __builtin_amdgcn_cosf(arev);
        const float sb = __builtin_amdgcn_sinf(arev);
        const float w2r = cb * cb - sb * sb, w2i = 2.0f * cb * sb;
        const float w3r = cb * w2r - sb * w2i, w3i = cb * w2i + sb * w2r;
        #pragma unroll
        for (int k = 0; k < 4; ++k) {
            const int b = 4 * k;
            float a1r = zr[b+1] * cb - zi[b+1] * sb,   a1i = zr[b+1] * sb + zi[b+1] * cb;
            float a2r = zr[b+2] * w2r - zi[b+2] * w2i, a2i = zr[b+2] * w2i + zi[b+2] * w2r;
            float a3r = zr[b+3] * w3r - zi[b+3] * w3i, a3i = zr[b+3] * w3i + zi[b+3] * w3r;
            float t0r = zr[b] + a2r, t0i = zi[b] + a2i;
            float t1r = zr[b] - a2r, t1i = zi[b] - a2i;
            float t2r = a1r + a3r, t2i = a1i + a3i;
            float t3r = a1r - a3r, t3i = a1i - a3i;
            zr[b]   = t0r + t2r;    zi[b]   = t0i + t2i;
            zr[b+2] = t0r - t2r;    zi[b+2] = t0i - t2i;
            zr[b+1] = t1r - sg * t3i; zi[b+1] = t1i + sg * t3r;
            zr[b+3] = t1r + sg * t3i; zi[b+3] = t1i - sg * t3r;
        }
    }
    {   // stage 2: stride 4 in m, twiddle W_{16Q}^{j*(p+rQ)} on inputs
        const float arev = sg * (float)p * (1.0f / (16.0f * (float)Q));
        const float cB = __builtin_amdgcn_cosf(arev);
        const float sB = __builtin_amdgcn_sinf(arev);
        #pragma unroll
        for (int r = 0; r < 4; ++r) {
            float kcc = kc[r], kss = sg * ks[r];
            float w1r = cB * kcc - sB * kss, w1i = sB * kcc + cB * kss;
            float w2r = w1r * w1r - w1i * w1i, w2i = 2.0f * w1r * w1i;
            float w3r = w1r * w2r - w1i * w2i, w3i = w1r * w2i + w1i * w2r;
            float a1r = zr[r+4] * w1r - zi[r+4] * w1i,   a1i = zr[r+4] * w1i + zi[r+4] * w1r;
            float a2r = zr[r+8] * w2r - zi[r+8] * w2i,   a2i = zr[r+8] * w2i + zi[r+8] * w2r;
            float a3r = zr[r+12] * w3r - zi[r+12] * w3i, a3i = zr[r+12] * w3i + zi[r+12] * w3r;
            float t0r = zr[r] + a2r, t0i = zi[r] + a2i;
            float t1r = zr[r] - a2r, t1i = zi[r] - a2i;
            float t2r = a1r + a3r, t2i = a1i + a3i;
            float t3r = a1r - a3r, t3i = a1i - a3i;
            zr[r]    = t0r + t2r;    zi[r]    = t0i + t2i;
            zr[r+8]  = t0r - t2r;    zi[r+8]  = t0i - t2i;
            zr[r+4]  = t1r - sg * t3i; zi[r+4]  = t1i + sg * t3r;
            zr[r+12] = t1r + sg * t3i; zi[r+12] = t1i - sg * t3r;
        }
    }
}

template <int SGN, int LOG2Q>
__device__ __forceinline__ void trip_dif(float* sre, float* sim, int t) {
    constexpr int Q = 1 << LOG2Q;
    const int p = t & (Q - 1);
    const int base = ((t >> LOG2Q) << (LOG2Q + 4)) + p;
    float zr[16], zi[16];
    #pragma unroll
    for (int m = 0; m < 16; ++m) { int ii = PAD32(base + (m << LOG2Q)); zr[m] = sre[ii]; zi[m] = sim[ii]; }
    dif_pair<SGN, Q>(zr, zi, p);
    #pragma unroll
    for (int m = 0; m < 16; ++m) { int ii = PAD32(base + (m << LOG2Q)); sre[ii] = zr[m]; sim[ii] = zi[m]; }
    __syncthreads();
}

template <int SGN, int LOG2Q>
__device__ __forceinline__ void trip_dit(float* sre, float* sim, int t) {
    constexpr int Q = 1 << LOG2Q;
    const int p = t & (Q - 1);
    const int base = ((t >> LOG2Q) << (LOG2Q + 4)) + p;
    float zr[16], zi[16];
    #pragma unroll
    for (int m = 0; m < 16; ++m) { int ii = PAD32(base + (m << LOG2Q)); zr[m] = sre[ii]; zi[m] = sim[ii]; }
    dit_pair<SGN, Q>(zr, zi, p);
    #pragma unroll
    for (int m = 0; m < 16; ++m) { int ii = PAD32(base + (m << LOG2Q)); sre[ii] = zr[m]; sim[ii] = zi[m]; }
    __syncthreads();
}

// single no-twiddle radix-4 stage on contiguous quads (DIF-last / DIT-first)
template <int SGN>
__device__ __forceinline__ void trip_nt(float* sre, float* sim, int t) {
    const float sg = (float)SGN;
    const int base = t << 4;
    float zr[16], zi[16];
    #pragma unroll
    for (int m = 0; m < 16; ++m) { int ii = PAD32(base + m); zr[m] = sre[ii]; zi[m] = sim[ii]; }
    #pragma unroll
    for (int k = 0; k < 4; ++k) {
        int b = 4 * k;
        float t0r = zr[b] + zr[b+2],   t0i = zi[b] + zi[b+2];
        float t1r = zr[b] - zr[b+2],   t1i = zi[b] - zi[b+2];
        float t2r = zr[b+1] + zr[b+3], t2i = zi[b+1] + zi[b+3];
        float t3r = zr[b+1] - zr[b+3], t3i = zi[b+1] - zi[b+3];
        zr[b]   = t0r + t2r;    zi[b]   = t0i + t2i;
        zr[b+2] = t0r - t2r;    zi[b+2] = t0i - t2i;
        zr[b+1] = t1r - sg * t3i; zi[b+1] = t1i + sg * t3r;
        zr[b+3] = t1r + sg * t3i; zi[b+3] = t1i - sg * t3r;
    }
    #pragma unroll
    for (int m = 0; m < 16; ++m) { int ii = PAD32(base + m); sre[ii] = zr[m]; sim[ii] = zi[m]; }
    __syncthreads();
}

// ---------------------------------------------------------------------------
// Mega-kernel, phase-local register discipline:
//   R2 post-mortem: the allocator pins this kernel at 64 VGPRs regardless of
//   launch_bounds/waves_per_eu hints, so any per-thread array that lives
//   across phases (R1/R2: xv[16], yv[16]) is spilled to scratch
//   (~372 KB/block -> 190 MB WRITE_SIZE, which was ~85% of runtime).
//   Fix: NO array outlives a phase.
//     - Pearson/min-max accumulate while streaming the global load; the pair
//       goes straight to LDS (sre=x, sim=y == FFT1 input z=x+iy, natural order)
//     - MI re-reads x,y from LDS (~1 us at LDS BW)
//     - FFT1 stage 1 is a normal LDS trip (LOG2Q=10) instead of register-held
// ---------------------------------------------------------------------------
__global__ __launch_bounds__(1024, 4) void k_main(const float* __restrict__ pred,
                                                  const float* __restrict__ targ,
                                                  const int* __restrict__ ip,
                                                  float* __restrict__ wpear,
                                                  float* __restrict__ wcos,
                                                  double* __restrict__ wnum,
                                                  double* __restrict__ wden,
                                                  float* __restrict__ wnmi) {
    __shared__ float sre[NPAD];
    __shared__ float sim[NPAD];
    __shared__ double dpart[16 * 5];
    __shared__ float fpart[16 * 4];
    __shared__ int   subhist[400];
    __shared__ float hxm[10], hym[10];
    __shared__ float mterm[128];
    __shared__ float sbounds[4];
    __shared__ float svalw[16];
    __shared__ int   sidxw[16];

    const int row = blockIdx.x;
    const int t = threadIdx.x;
    const int w = t >> 6;
    const int lane = t & 63;

    const float* xg = pred + (size_t)ip[0] * (size_t)BB * SS + (size_t)row * SS;
    const float* yg = targ + (size_t)row * SS;

    // ---- Load + Pearson sums (fp64) + min/max, streaming; park x,y in LDS.
    {
        double sx = 0, sy = 0, sxy = 0, sxx = 0, syy = 0;
        float xmn = 3.4e38f, xmx = -3.4e38f, ymn = 3.4e38f, ymx = -3.4e38f;
        #pragma unroll
        for (int m = 0; m < 16; ++m) {
            int n = t + (m << 10);
            float a = xg[n], b = yg[n];
            int ii = PAD32(n);
            sre[ii] = a; sim[ii] = b;
            sx += (double)a; sy += (double)b;
            sxy += (double)a * (double)b;
            sxx += (double)a * (double)a;
            syy += (double)b * (double)b;
            xmn = fminf(xmn, a); xmx = fmaxf(xmx, a);
            ymn = fminf(ymn, b); ymx = fmaxf(ymx, b);
        }
        #pragma unroll
        for (int o = 32; o > 0; o >>= 1) {
            sx += __shfl_down(sx, o, 64);  sy += __shfl_down(sy, o, 64);
            sxy += __shfl_down(sxy, o, 64);
            sxx += __shfl_down(sxx, o, 64); syy += __shfl_down(syy, o, 64);
            xmn = fminf(xmn, __shfl_down(xmn, o, 64));
            xmx = fmaxf(xmx, __shfl_down(xmx, o, 64));
            ymn = fminf(ymn, __shfl_down(ymn, o, 64));
            ymx = fmaxf(ymx, __shfl_down(ymx, o, 64));
        }
        if (lane == 0) {
            dpart[w*5+0] = sx; dpart[w*5+1] = sy; dpart[w*5+2] = sxy;
            dpart[w*5+3] = sxx; dpart[w*5+4] = syy;
            fpart[w*4+0] = xmn; fpart[w*4+1] = xmx; fpart[w*4+2] = ymn; fpart[w*4+3] = ymx;
        }
    }
    if (t < 400) subhist[t] = 0;
    __syncthreads();
    if (t == 0) {
        double v0=0,v1=0,v2=0,v3=0,v4=0;
        float b0=fpart[0], b1=fpart[1], b2=fpart[2], b3=fpart[3];
        for (int q = 0; q < 16; ++q) {
            v0 += dpart[q*5]; v1 += dpart[q*5+1]; v2 += dpart[q*5+2];
            v3 += dpart[q*5+3]; v4 += dpart[q*5+4];
            b0 = fminf(b0, fpart[q*4]);   b1 = fmaxf(b1, fpart[q*4+1]);
            b2 = fminf(b2, fpart[q*4+2]); b3 = fmaxf(b3, fpart[q*4+3]);
        }
        double N = (double)SS;
        double num = N * v2 - v0 * v1;
        double den = sqrt((N * v3 - v0 * v0) * (N * v4 - v1 * v1));
        wpear[row] = (float)(1.0 - num / den);
        sbounds[0] = b0; sbounds[1] = b1; sbounds[2] = b2; sbounds[3] = b3;
    }
    __syncthreads();

    // ---- MI histogram (x,y re-read from LDS; 4 sub-hists cut atomic contention)
    {
        const float x0 = sbounds[0], bwx = (sbounds[1] - x0) / 10.0f;
        const float y0 = sbounds[2], bwy = (sbounds[3] - y0) / 10.0f;
        int* hsub = subhist + ((t >> 6) & 3) * 100;
        #pragma unroll
        for (int m = 0; m < 16; ++m) {
            int ii = PAD32(t + (m << 10));
            float a = sre[ii], b = sim[ii];
            int ix = (int)((a - x0) / bwx); ix = min(max(ix, 0), 9);
            int iy = (int)((b - y0) / bwy); iy = min(max(iy, 0), 9);
            atomicAdd(&hsub[ix * 10 + iy], 1);
        }
    }
    __syncthreads();
    if (t < 100) subhist[t] = subhist[t] + subhist[100+t] + subhist[200+t] + subhist[300+t];
    __syncthreads();
    if (t < 10) {
        int s1 = 0, s2 = 0;
        for (int j = 0; j < 10; ++j) { s1 += subhist[t*10+j]; s2 += subhist[j*10+t]; }
        hxm[t] = (float)s1; hym[t] = (float)s2;
    }
    __syncthreads();
    {
        float term = 0.0f;
        if (t < 100) {
            const float denom = 8388608.0f, eps = 1e-8f;
            float pxy = (float)subhist[t] / denom;
            float px = hxm[t / 10] / denom, py = hym[t % 10] / denom;
            term = pxy * logf((pxy + eps) / (px * py + eps));
        }
        if (t < 128) mterm[t] = (t < 100) ? term : 0.0f;
    }
    __syncthreads();
    if (t == 0) {
        const float denom = 8388608.0f, eps = 1e-8f;
        float mi = 0.0f;
        for (int q = 0; q < 100; ++q) mi += mterm[q];
        float hxe = 0.0f, hye = 0.0f;
        for (int q = 0; q < 10; ++q) {
            float px = hxm[q] / denom, py = hym[q] / denom;
            hxe -= px * logf(px + eps);
            hye -= py * logf(py + eps);
        }
        wnmi[row] = mi / (0.5f * (hxe + hye));
    }
    __syncthreads();

    // ---- FFT1 (shared): z = x + i*y already in LDS in natural order.
    trip_dif<-1, 10>(sre, sim, t);  // strides 4096,1024
    trip_dif<-1, 6>(sre, sim, t);   // strides 256,64
    trip_dif<-1, 2>(sre, sim, t);   // strides 16,4
    trip_nt<-1>(sre, sim, t);       // stride 1

    // ---- Fused unpack: power sums (unwindowed) + phase-correlation C from
    //      the Hann-convolved spectrum (Zw[k] = 0.5 Z[k] - 0.25 (Z[k-1]+Z[k+1]),
    //      exact for the periodic Hann window). All reads before the barrier,
    //      all writes after (C values parked in registers).
    {
        double anum = 0.0, aden = 0.0;
        float crv[8], civ[8];
        #pragma unroll
        for (int m = 0; m < 8; ++m) {
            int k = t + (m << 10);
            int km = (SS - k) & (SS - 1);
            int qa = digrev4(k), qb = digrev4(km);
            float ar  = sre[PAD32(qa)], ai  = sim[PAD32(qa)];
            float cr0 = sre[PAD32(qb)], ci0 = sim[PAD32(qb)];
            // power spectrum terms (unwindowed)
            float xr = 0.5f * (ar + cr0), xi = 0.5f * (ai - ci0);
            float yr = 0.5f * (ai + ci0), yi = 0.5f * (cr0 - ar);
            float xp = xr * xr + xi * xi;
            float tp = yr * yr + yi * yi;
            anum += (double)fabsf(xp - tp);
            aden += (double)tp;
            // Hann conv: Zw[k] = 0.5 Z[k] - 0.25 (Z[k-1] + Z[k+1])
            int qap = digrev4((k + 1) & (SS - 1));
            int qam = digrev4((k - 1) & (SS - 1));
            int qbp = digrev4((km + 1) & (SS - 1));
            int qbm = digrev4((km - 1) & (SS - 1));
            float apr = sre[PAD32(qap)], api = sim[PAD32(qap)];
            float amr = sre[PAD32(qam)], ami = sim[PAD32(qam)];
            float bpr = sre[PAD32(qbp)], bpi = sim[PAD32(qbp)];
            float bmr = sre[PAD32(qbm)], bmi = sim[PAD32(qbm)];
            float zwr = 0.5f * ar  - 0.25f * (apr + amr);
            float zwi = 0.5f * ai  - 0.25f * (api + ami);
            float vwr = 0.5f * cr0 - 0.25f * (bpr + bmr);
            float vwi = 0.5f * ci0 - 0.25f * (bpi + bmi);
            // unpack windowed spectra Xw, Yw
            float xwr = 0.5f * (zwr + vwr), xwi = 0.5f * (zwi - vwi);
            float ywr = 0.5f * (zwi + vwi), ywi = 0.5f * (vwr - zwr);
            // C = Xw * conj(Yw) / |.|
            float cr = xwr * ywr + xwi * ywi;
            float ci = xwi * ywr - xwr * ywi;
            float mag = sqrtf(cr * cr + ci * ci);
            crv[m] = cr / mag; civ[m] = ci / mag;
        }
        float c8 = 0.0f;
        if (t == 0) {   // k = 8192 (self-conjugate)
            int q  = digrev4(8192);
            int qp = digrev4(8193);
            int qm = digrev4(8191);
            float ar = sre[PAD32(q)],  ai = sim[PAD32(q)];
            anum += (double)fabsf(ar * ar - ai * ai);
            aden += (double)(ai * ai);
            float zwr = 0.5f * ar - 0.25f * (sre[PAD32(qp)] + sre[PAD32(qm)]);
            float zwi = 0.5f * ai - 0.25f * (sim[PAD32(qp)] + sim[PAD32(qm)]);
            float pr = zwr * zwi;          // Xw real, Yw real at Nyquist
            c8 = pr / fabsf(pr);
        }
        #pragma unroll
        for (int o = 32; o > 0; o >>= 1) {
            anum += __shfl_down(anum, o, 64);
            aden += __shfl_down(aden, o, 64);
        }
        if (lane == 0) { dpart[w*2] = anum; dpart[w*2+1] = aden; }
        __syncthreads();   // all spectrum reads done; safe to overwrite
        #pragma unroll
        for (int m = 0; m < 8; ++m) {
            int k = t + (m << 10);
            int km = (SS - k) & (SS - 1);
            int q = digrev4(k), q2 = digrev4(km);
            sre[PAD32(q)]  = crv[m]; sim[PAD32(q)]  = civ[m];
            sre[PAD32(q2)] = crv[m]; sim[PAD32(q2)] = -civ[m];
        }
        if (t == 0) {
            int q = digrev4(8192);
            sre[PAD32(q)] = c8; sim[PAD32(q)] = 0.0f;
            double a = 0, b = 0;
            for (int q2_ = 0; q2_ < 16; ++q2_) { a += dpart[q2_*2]; b += dpart[q2_*2+1]; }
            wnum[row] = a; wden[row] = b;
        }
    }
    __syncthreads();

    // ---- FFT3: inverse DIT (rev input -> natural output), argmax from regs
    trip_nt<1>(sre, sim, t);
    trip_dit<1, 2>(sre, sim, t);
    trip_dit<1, 6>(sre, sim, t);
    {
        float zr[16], zi[16];
        #pragma unroll
        for (int m = 0; m < 16; ++m) { int ii = PAD32(t + (m << 10)); zr[m] = sre[ii]; zi[m] = sim[ii]; }
        dit_pair<1, 1024>(zr, zi, t);
        float bv = zr[0]; int bi = t;
        #pragma unroll
        for (int m = 1; m < 16; ++m) {
            int n = t + (m << 10);
            if (zr[m] > bv) { bv = zr[m]; bi = n; }
        }
        #pragma unroll
        for (int o = 32; o > 0; o >>= 1) {
            float v2 = __shfl_down(bv, o, 64);
            int i2 = __shfl_down(bi, o, 64);
            if (v2 > bv || (v2 == bv && i2 < bi)) { bv = v2; bi = i2; }
        }
        if (lane == 0) { svalw[w] = bv; sidxw[w] = bi; }
    }
    __syncthreads();
    if (t == 0) {
        float bv = svalw[0]; int bi = sidxw[0];
        for (int q = 1; q < 16; ++q) {
            if (svalw[q] > bv || (svalw[q] == bv && sidxw[q] < bi)) { bv = svalw[q]; bi = sidxw[q]; }
        }
        wcos[row] = cosf(TPIF * (float)bi / 16384.0f);
    }
}

// ---------------------------------------------------------------------------
// Final combine (reads epoch on-device; graph-safe). Wave-shuffle reductions.
// ---------------------------------------------------------------------------
__global__ __launch_bounds__(512) void k_combine(const float* __restrict__ wpear,
                                                 const float* __restrict__ wcos,
                                                 const double* __restrict__ wnum,
                                                 const double* __restrict__ wden,
                                                 const float* __restrict__ wnmi,
                                                 const int* __restrict__ ep,
                                                 float* __restrict__ out) {
    __shared__ double dp[8 * 5];
    const int tid = threadIdx.x;
    const int w = tid >> 6, lane = tid & 63;
    double v0 = (double)wpear[tid], v1 = (double)wcos[tid];
    double v2 = wnum[tid], v3 = wden[tid], v4 = (double)wnmi[tid];
    #pragma unroll
    for (int o = 32; o > 0; o >>= 1) {
        v0 += __shfl_down(v0, o, 64); v1 += __shfl_down(v1, o, 64);
        v2 += __shfl_down(v2, o, 64); v3 += __shfl_down(v3, o, 64);
        v4 += __shfl_down(v4, o, 64);
    }
    if (lane == 0) {
        dp[w*5+0] = v0; dp[w*5+1] = v1; dp[w*5+2] = v2; dp[w*5+3] = v3; dp[w*5+4] = v4;
    }
    __syncthreads();
    if (tid == 0) {
        double s0=0,s1=0,s2=0,s3=0,s4=0;
        for (int q = 0; q < 8; ++q) {
            s0 += dp[q*5]; s1 += dp[q*5+1]; s2 += dp[q*5+2]; s3 += dp[q*5+3]; s4 += dp[q*5+4];
        }
        int epoch = ep[0];
        double loss = s0 / 512.0;
        if (epoch >= 400) {
            loss += 1.0 - s1 / 512.0;
            loss += s2 / s3;
        }
        if (epoch >= 700) {
            loss += 1.0 - s4 / 512.0;
        }
        out[0] = (float)loss;
    }
}

// ---------------------------------------------------------------------------
extern "C" void kernel_launch(void* const* d_in, const int* in_sizes, int n_in,
                              void* d_out, int out_size, void* d_ws, size_t ws_size,
                              hipStream_t stream) {
    const float* pred = (const float*)d_in[0];   // [2, 512, 16384] f32
    const float* targ = (const float*)d_in[1];   // [512, 16384] f32
    const int* ip = (const int*)d_in[2];         // scalar i
    const int* ep = (const int*)d_in[3];         // scalar epoch
    float* out = (float*)d_out;

    double* wnum = (double*)d_ws;                // [512]
    double* wden = wnum + BB;                    // [512]
    float* wpear = (float*)(wden + BB);          // [512]
    float* wcos = wpear + BB;                    // [512]
    float* wnmi = wcos + BB;                     // [512]

    k_main<<<dim3(BB), dim3(1024), 0, stream>>>(pred, targ, ip, wpear, wcos, wnum, wden, wnmi);
    k_combine<<<dim3(1), dim3(512), 0, stream>>>(wpear, wcos, wnum, wden, wnmi, ep, out);
}

// Round 4
// 214.678 us; speedup vs baseline: 1.1926x; 1.1926x over previous
//
#include <hip/hip_runtime.h>
#include <math.h>

#define BB 512
#define SS 16384
#define TPIF 6.28318530717958647692f

// pad so lane-strides {1,4,16-ish} are ~conflict-free (b32)
#define PAD32(i) ((i) + ((i) >> 5) + ((i) >> 10))
#define NPAD 16912   // PAD32(16383)=16909 < 16912

// base-4 digit reversal of 14-bit index (7 digits)
__device__ __forceinline__ int digrev4(int n) {
    unsigned x = __brev((unsigned)n) >> (32 - 14);
    return (int)(((x & 0x1555u) << 1) | ((x >> 1) & 0x1555u));
}

// ---------------------------------------------------------------------------
// R4 design rule: the allocator pins this kernel at 64 VGPRs (R0-R3 evidence:
// VGPR_Count=64 under every launch_bounds/waves_per_eu hint) and the fused
// radix-16 trips (32 data VGPRs + ~20 temps + pipelined loads) spill INSIDE
// every trip (~190 MB/dispatch scratch, constant across R0-R3). So: all FFT
// stages are single radix-4 butterflies -- max ~30 live VGPRs anywhere.
// 7 stages per 16K FFT, one __syncthreads per stage.
// ---------------------------------------------------------------------------

// one radix-4 DIF stage: element stride Q, block 4Q, twiddle W_{4Q}^{m*p} on
// outputs. Thread does 4 butterflies j = 4t+c (contiguous -> lane stride 4).
template <int SGN, int LOG2Q>
__device__ __forceinline__ void stage_dif4(float* sre, float* sim, int t) {
    constexpr int Q = 1 << LOG2Q;
    const float sg = (float)SGN;
    #pragma unroll 2
    for (int c = 0; c < 4; ++c) {
        const int j = 4 * t + c;
        const int g = j >> LOG2Q;
        const int p = j & (Q - 1);
        const int e0 = (g << (LOG2Q + 2)) + p;
        const int i0 = PAD32(e0);
        const int i1 = PAD32(e0 + Q);
        const int i2 = PAD32(e0 + 2 * Q);
        const int i3 = PAD32(e0 + 3 * Q);
        float z0r = sre[i0], z0i = sim[i0];
        float z1r = sre[i1], z1i = sim[i1];
        float z2r = sre[i2], z2i = sim[i2];
        float z3r = sre[i3], z3i = sim[i3];
        float t0r = z0r + z2r, t0i = z0i + z2i;
        float t1r = z0r - z2r, t1i = z0i - z2i;
        float t2r = z1r + z3r, t2i = z1i + z3i;
        float t3r = z1r - z3r, t3i = z1i - z3i;
        float b0r = t0r + t2r, b0i = t0i + t2i;
        float b2r = t0r - t2r, b2i = t0i - t2i;
        float b1r = t1r - sg * t3i, b1i = t1i + sg * t3r;
        float b3r = t1r + sg * t3i, b3i = t1i - sg * t3r;
        const float a = sg * (float)p * (1.0f / (4.0f * (float)Q));  // revolutions
        const float cb = __builtin_amdgcn_cosf(a);
        const float sb = __builtin_amdgcn_sinf(a);
        const float w2r = cb * cb - sb * sb, w2i = 2.0f * cb * sb;
        const float w3r = cb * w2r - sb * w2i, w3i = cb * w2i + sb * w2r;
        sre[i0] = b0r;                    sim[i0] = b0i;
        sre[i1] = b1r * cb - b1i * sb;    sim[i1] = b1r * sb + b1i * cb;
        sre[i2] = b2r * w2r - b2i * w2i;  sim[i2] = b2r * w2i + b2i * w2r;
        sre[i3] = b3r * w3r - b3i * w3i;  sim[i3] = b3r * w3i + b3i * w3r;
    }
    __syncthreads();
}

// one radix-4 DIT stage: element stride Q, block 4Q, twiddle W_{4Q}^{m*p} on
// INPUTS (inverse transform uses SGN=+1).
template <int SGN, int LOG2Q>
__device__ __forceinline__ void stage_dit4(float* sre, float* sim, int t) {
    constexpr int Q = 1 << LOG2Q;
    const float sg = (float)SGN;
    #pragma unroll 2
    for (int c = 0; c < 4; ++c) {
        const int j = 4 * t + c;
        const int g = j >> LOG2Q;
        const int p = j & (Q - 1);
        const int e0 = (g << (LOG2Q + 2)) + p;
        const int i0 = PAD32(e0);
        const int i1 = PAD32(e0 + Q);
        const int i2 = PAD32(e0 + 2 * Q);
        const int i3 = PAD32(e0 + 3 * Q);
        float z0r = sre[i0], z0i = sim[i0];
        float z1r = sre[i1], z1i = sim[i1];
        float z2r = sre[i2], z2i = sim[i2];
        float z3r = sre[i3], z3i = sim[i3];
        const float a = sg * (float)p * (1.0f / (4.0f * (float)Q));  // revolutions
        const float cb = __builtin_amdgcn_cosf(a);
        const float sb = __builtin_amdgcn_sinf(a);
        const float w2r = cb * cb - sb * sb, w2i = 2.0f * cb * sb;
        const float w3r = cb * w2r - sb * w2i, w3i = cb * w2i + sb * w2r;
        float a1r = z1r * cb - z1i * sb,   a1i = z1r * sb + z1i * cb;
        float a2r = z2r * w2r - z2i * w2i, a2i = z2r * w2i + z2i * w2r;
        float a3r = z3r * w3r - z3i * w3i, a3i = z3r * w3i + z3i * w3r;
        float t0r = z0r + a2r, t0i = z0i + a2i;
        float t1r = z0r - a2r, t1i = z0i - a2i;
        float t2r = a1r + a3r, t2i = a1i + a3i;
        float t3r = a1r - a3r, t3i = a1i - a3i;
        sre[i0] = t0r + t2r;       sim[i0] = t0i + t2i;
        sre[i2] = t0r - t2r;       sim[i2] = t0i - t2i;
        sre[i1] = t1r - sg * t3i;  sim[i1] = t1i + sg * t3r;
        sre[i3] = t1r + sg * t3i;  sim[i3] = t1i - sg * t3r;
    }
    __syncthreads();
}

// ---------------------------------------------------------------------------
// Mega-kernel: one block per row does Pearson, MI, ONE forward FFT (shared by
// power spectrum AND phase correlation via the Hann spectral identity
// Zw[k] = 0.5 Z[k] - 0.25 (Z[k-1]+Z[k+1]), exact for the periodic window),
// and the inverse FFT for the phase-correlation argmax.
// ---------------------------------------------------------------------------
__global__ __launch_bounds__(1024, 4) void k_main(const float* __restrict__ pred,
                                                  const float* __restrict__ targ,
                                                  const int* __restrict__ ip,
                                                  float* __restrict__ wpear,
                                                  float* __restrict__ wcos,
                                                  double* __restrict__ wnum,
                                                  double* __restrict__ wden,
                                                  float* __restrict__ wnmi) {
    __shared__ float sre[NPAD];
    __shared__ float sim[NPAD];
    __shared__ double dpart[16 * 5];
    __shared__ float fpart[16 * 4];
    __shared__ int   subhist[400];
    __shared__ float hxm[10], hym[10];
    __shared__ float mterm[128];
    __shared__ float sbounds[4];
    __shared__ float svalw[16];
    __shared__ int   sidxw[16];

    const int row = blockIdx.x;
    const int t = threadIdx.x;
    const int w = t >> 6;
    const int lane = t & 63;

    const float* xg = pred + (size_t)ip[0] * (size_t)BB * SS + (size_t)row * SS;
    const float* yg = targ + (size_t)row * SS;

    // ---- Load (float4) + Pearson sums (fp64) + min/max, streaming into LDS
    //      (sre = x, sim = y == FFT1 input z = x + i y, natural order).
    {
        const float4* xg4 = reinterpret_cast<const float4*>(xg);
        const float4* yg4 = reinterpret_cast<const float4*>(yg);
        double sx = 0, sy = 0, sxy = 0, sxx = 0, syy = 0;
        float xmn = 3.4e38f, xmx = -3.4e38f, ymn = 3.4e38f, ymx = -3.4e38f;
        #pragma unroll
        for (int m2 = 0; m2 < 4; ++m2) {
            int idx = t + (m2 << 10);          // float4 index
            float4 a = xg4[idx];
            float4 b = yg4[idx];
            int n0 = idx << 2;
            sre[PAD32(n0 + 0)] = a.x; sim[PAD32(n0 + 0)] = b.x;
            sre[PAD32(n0 + 1)] = a.y; sim[PAD32(n0 + 1)] = b.y;
            sre[PAD32(n0 + 2)] = a.z; sim[PAD32(n0 + 2)] = b.z;
            sre[PAD32(n0 + 3)] = a.w; sim[PAD32(n0 + 3)] = b.w;
            float av[4] = {a.x, a.y, a.z, a.w};
            float bv[4] = {b.x, b.y, b.z, b.w};
            #pragma unroll
            for (int c = 0; c < 4; ++c) {
                float aa = av[c], bb = bv[c];
                sx += (double)aa; sy += (double)bb;
                sxy += (double)aa * (double)bb;
                sxx += (double)aa * (double)aa;
                syy += (double)bb * (double)bb;
                xmn = fminf(xmn, aa); xmx = fmaxf(xmx, aa);
                ymn = fminf(ymn, bb); ymx = fmaxf(ymx, bb);
            }
        }
        #pragma unroll
        for (int o = 32; o > 0; o >>= 1) {
            sx += __shfl_down(sx, o, 64);  sy += __shfl_down(sy, o, 64);
            sxy += __shfl_down(sxy, o, 64);
            sxx += __shfl_down(sxx, o, 64); syy += __shfl_down(syy, o, 64);
            xmn = fminf(xmn, __shfl_down(xmn, o, 64));
            xmx = fmaxf(xmx, __shfl_down(xmx, o, 64));
            ymn = fminf(ymn, __shfl_down(ymn, o, 64));
            ymx = fmaxf(ymx, __shfl_down(ymx, o, 64));
        }
        if (lane == 0) {
            dpart[w*5+0] = sx; dpart[w*5+1] = sy; dpart[w*5+2] = sxy;
            dpart[w*5+3] = sxx; dpart[w*5+4] = syy;
            fpart[w*4+0] = xmn; fpart[w*4+1] = xmx; fpart[w*4+2] = ymn; fpart[w*4+3] = ymx;
        }
    }
    if (t < 400) subhist[t] = 0;
    __syncthreads();
    if (t == 0) {
        double v0=0,v1=0,v2=0,v3=0,v4=0;
        float b0=fpart[0], b1=fpart[1], b2=fpart[2], b3=fpart[3];
        for (int q = 0; q < 16; ++q) {
            v0 += dpart[q*5]; v1 += dpart[q*5+1]; v2 += dpart[q*5+2];
            v3 += dpart[q*5+3]; v4 += dpart[q*5+4];
            b0 = fminf(b0, fpart[q*4]);   b1 = fmaxf(b1, fpart[q*4+1]);
            b2 = fminf(b2, fpart[q*4+2]); b3 = fmaxf(b3, fpart[q*4+3]);
        }
        double N = (double)SS;
        double num = N * v2 - v0 * v1;
        double den = sqrt((N * v3 - v0 * v0) * (N * v4 - v1 * v1));
        wpear[row] = (float)(1.0 - num / den);
        sbounds[0] = b0; sbounds[1] = b1; sbounds[2] = b2; sbounds[3] = b3;
    }
    __syncthreads();

    // ---- MI histogram (x,y re-read from LDS; 4 sub-hists cut atomic contention)
    {
        const float x0 = sbounds[0], bwx = (sbounds[1] - x0) / 10.0f;
        const float y0 = sbounds[2], bwy = (sbounds[3] - y0) / 10.0f;
        int* hsub = subhist + ((t >> 6) & 3) * 100;
        #pragma unroll 2
        for (int m = 0; m < 16; ++m) {
            int ii = PAD32(t + (m << 10));
            float a = sre[ii], b = sim[ii];
            int ix = (int)((a - x0) / bwx); ix = min(max(ix, 0), 9);
            int iy = (int)((b - y0) / bwy); iy = min(max(iy, 0), 9);
            atomicAdd(&hsub[ix * 10 + iy], 1);
        }
    }
    __syncthreads();
    if (t < 100) subhist[t] = subhist[t] + subhist[100+t] + subhist[200+t] + subhist[300+t];
    __syncthreads();
    if (t < 10) {
        int s1 = 0, s2 = 0;
        for (int j = 0; j < 10; ++j) { s1 += subhist[t*10+j]; s2 += subhist[j*10+t]; }
        hxm[t] = (float)s1; hym[t] = (float)s2;
    }
    __syncthreads();
    {
        float term = 0.0f;
        if (t < 100) {
            const float denom = 8388608.0f, eps = 1e-8f;
            float pxy = (float)subhist[t] / denom;
            float px = hxm[t / 10] / denom, py = hym[t % 10] / denom;
            term = pxy * logf((pxy + eps) / (px * py + eps));
        }
        if (t < 128) mterm[t] = (t < 100) ? term : 0.0f;
    }
    __syncthreads();
    if (t == 0) {
        const float denom = 8388608.0f, eps = 1e-8f;
        float mi = 0.0f;
        for (int q = 0; q < 100; ++q) mi += mterm[q];
        float hxe = 0.0f, hye = 0.0f;
        for (int q = 0; q < 10; ++q) {
            float px = hxm[q] / denom, py = hym[q] / denom;
            hxe -= px * logf(px + eps);
            hye -= py * logf(py + eps);
        }
        wnmi[row] = mi / (0.5f * (hxe + hye));
    }
    __syncthreads();

    // ---- FFT1 (shared forward DIF, radix-4 x7): natural -> digit-reversed
    stage_dif4<-1, 12>(sre, sim, t);
    stage_dif4<-1, 10>(sre, sim, t);
    stage_dif4<-1,  8>(sre, sim, t);
    stage_dif4<-1,  6>(sre, sim, t);
    stage_dif4<-1,  4>(sre, sim, t);
    stage_dif4<-1,  2>(sre, sim, t);
    stage_dif4<-1,  0>(sre, sim, t);

    // ---- Fused unpack: power sums (unwindowed) + phase-correlation C from
    //      the Hann-convolved spectrum. Reads before barrier, writes after
    //      (C parked in crv/civ: 16 VGPRs across ONE barrier; unroll 1 caps
    //      per-iteration pressure).
    {
        double anum = 0.0, aden = 0.0;
        float crv[8], civ[8];
        #pragma unroll 1
        for (int m = 0; m < 8; ++m) {
            int k = t + (m << 10);
            int km = (SS - k) & (SS - 1);
            int qa = digrev4(k), qb = digrev4(km);
            float ar  = sre[PAD32(qa)], ai  = sim[PAD32(qa)];
            float cr0 = sre[PAD32(qb)], ci0 = sim[PAD32(qb)];
            // power spectrum terms (unwindowed)
            float xr = 0.5f * (ar + cr0), xi = 0.5f * (ai - ci0);
            float yr = 0.5f * (ai + ci0), yi = 0.5f * (cr0 - ar);
            float xp = xr * xr + xi * xi;
            float tp = yr * yr + yi * yi;
            anum += (double)fabsf(xp - tp);
            aden += (double)tp;
            // Hann conv: Zw[k] = 0.5 Z[k] - 0.25 (Z[k-1] + Z[k+1])
            int qap = digrev4((k + 1) & (SS - 1));
            int qam = digrev4((k - 1) & (SS - 1));
            int qbp = digrev4((km + 1) & (SS - 1));
            int qbm = digrev4((km - 1) & (SS - 1));
            float apr = sre[PAD32(qap)], api = sim[PAD32(qap)];
            float amr = sre[PAD32(qam)], ami = sim[PAD32(qam)];
            float bpr = sre[PAD32(qbp)], bpi = sim[PAD32(qbp)];
            float bmr = sre[PAD32(qbm)], bmi = sim[PAD32(qbm)];
            float zwr = 0.5f * ar  - 0.25f * (apr + amr);
            float zwi = 0.5f * ai  - 0.25f * (api + ami);
            float vwr = 0.5f * cr0 - 0.25f * (bpr + bmr);
            float vwi = 0.5f * ci0 - 0.25f * (bpi + bmi);
            // unpack windowed spectra Xw, Yw
            float xwr = 0.5f * (zwr + vwr), xwi = 0.5f * (zwi - vwi);
            float ywr = 0.5f * (zwi + vwi), ywi = 0.5f * (vwr - zwr);
            // C = Xw * conj(Yw) / |.|
            float cr = xwr * ywr + xwi * ywi;
            float ci = xwi * ywr - xwr * ywi;
            float mag = sqrtf(cr * cr + ci * ci);
            crv[m] = cr / mag; civ[m] = ci / mag;
        }
        float c8 = 0.0f;
        if (t == 0) {   // k = 8192 (self-conjugate)
            int q  = digrev4(8192);
            int qp = digrev4(8193);
            int qm = digrev4(8191);
            float ar = sre[PAD32(q)],  ai = sim[PAD32(q)];
            anum += (double)fabsf(ar * ar - ai * ai);
            aden += (double)(ai * ai);
            float zwr = 0.5f * ar - 0.25f * (sre[PAD32(qp)] + sre[PAD32(qm)]);
            float zwi = 0.5f * ai - 0.25f * (sim[PAD32(qp)] + sim[PAD32(qm)]);
            float pr = zwr * zwi;          // Xw real, Yw real at Nyquist
            c8 = pr / fabsf(pr);
        }
        #pragma unroll
        for (int o = 32; o > 0; o >>= 1) {
            anum += __shfl_down(anum, o, 64);
            aden += __shfl_down(aden, o, 64);
        }
        if (lane == 0) { dpart[w*2] = anum; dpart[w*2+1] = aden; }
        __syncthreads();   // all spectrum reads done; safe to overwrite
        #pragma unroll
        for (int m = 0; m < 8; ++m) {
            int k = t + (m << 10);
            int km = (SS - k) & (SS - 1);
            int q = digrev4(k), q2 = digrev4(km);
            sre[PAD32(q)]  = crv[m]; sim[PAD32(q)]  = civ[m];
            sre[PAD32(q2)] = crv[m]; sim[PAD32(q2)] = -civ[m];
        }
        if (t == 0) {
            int q = digrev4(8192);
            sre[PAD32(q)] = c8; sim[PAD32(q)] = 0.0f;
            double a = 0, b = 0;
            for (int q2_ = 0; q2_ < 16; ++q2_) { a += dpart[q2_*2]; b += dpart[q2_*2+1]; }
            wnum[row] = a; wden[row] = b;
        }
    }
    __syncthreads();

    // ---- FFT3 (inverse DIT, radix-4 x7): digit-reversed -> natural order
    stage_dit4<1,  0>(sre, sim, t);
    stage_dit4<1,  2>(sre, sim, t);
    stage_dit4<1,  4>(sre, sim, t);
    stage_dit4<1,  6>(sre, sim, t);
    stage_dit4<1,  8>(sre, sim, t);
    stage_dit4<1, 10>(sre, sim, t);
    stage_dit4<1, 12>(sre, sim, t);

    // ---- argmax of real part (natural order), scalar running max (no arrays)
    {
        float bv = -3.4e38f; int bi = 0;
        #pragma unroll
        for (int m = 0; m < 16; ++m) {
            int n = t + (m << 10);
            float v = sre[PAD32(n)];
            if (v > bv) { bv = v; bi = n; }
        }
        #pragma unroll
        for (int o = 32; o > 0; o >>= 1) {
            float v2 = __shfl_down(bv, o, 64);
            int i2 = __shfl_down(bi, o, 64);
            if (v2 > bv || (v2 == bv && i2 < bi)) { bv = v2; bi = i2; }
        }
        if (lane == 0) { svalw[w] = bv; sidxw[w] = bi; }
    }
    __syncthreads();
    if (t == 0) {
        float bv = svalw[0]; int bi = sidxw[0];
        for (int q = 1; q < 16; ++q) {
            if (svalw[q] > bv || (svalw[q] == bv && sidxw[q] < bi)) { bv = svalw[q]; bi = sidxw[q]; }
        }
        wcos[row] = cosf(TPIF * (float)bi / 16384.0f);
    }
}

// ---------------------------------------------------------------------------
// Final combine (reads epoch on-device; graph-safe). Wave-shuffle reductions.
// ---------------------------------------------------------------------------
__global__ __launch_bounds__(512) void k_combine(const float* __restrict__ wpear,
                                                 const float* __restrict__ wcos,
                                                 const double* __restrict__ wnum,
                                                 const double* __restrict__ wden,
                                                 const float* __restrict__ wnmi,
                                                 const int* __restrict__ ep,
                                                 float* __restrict__ out) {
    __shared__ double dp[8 * 5];
    const int tid = threadIdx.x;
    const int w = tid >> 6, lane = tid & 63;
    double v0 = (double)wpear[tid], v1 = (double)wcos[tid];
    double v2 = wnum[tid], v3 = wden[tid], v4 = (double)wnmi[tid];
    #pragma unroll
    for (int o = 32; o > 0; o >>= 1) {
        v0 += __shfl_down(v0, o, 64); v1 += __shfl_down(v1, o, 64);
        v2 += __shfl_down(v2, o, 64); v3 += __shfl_down(v3, o, 64);
        v4 += __shfl_down(v4, o, 64);
    }
    if (lane == 0) {
        dp[w*5+0] = v0; dp[w*5+1] = v1; dp[w*5+2] = v2; dp[w*5+3] = v3; dp[w*5+4] = v4;
    }
    __syncthreads();
    if (tid == 0) {
        double s0=0,s1=0,s2=0,s3=0,s4=0;
        for (int q = 0; q < 8; ++q) {
            s0 += dp[q*5]; s1 += dp[q*5+1]; s2 += dp[q*5+2]; s3 += dp[q*5+3]; s4 += dp[q*5+4];
        }
        int epoch = ep[0];
        double loss = s0 / 512.0;
        if (epoch >= 400) {
            loss += 1.0 - s1 / 512.0;
            loss += s2 / s3;
        }
        if (epoch >= 700) {
            loss += 1.0 - s4 / 512.0;
        }
        out[0] = (float)loss;
    }
}

// ---------------------------------------------------------------------------
extern "C" void kernel_launch(void* const* d_in, const int* in_sizes, int n_in,
                              void* d_out, int out_size, void* d_ws, size_t ws_size,
                              hipStream_t stream) {
    const float* pred = (const float*)d_in[0];   // [2, 512, 16384] f32
    const float* targ = (const float*)d_in[1];   // [512, 16384] f32
    const int* ip = (const int*)d_in[2];         // scalar i
    const int* ep = (const int*)d_in[3];         // scalar epoch
    float* out = (float*)d_out;

    double* wnum = (double*)d_ws;                // [512]
    double* wden = wnum + BB;                    // [512]
    float* wpear = (float*)(wden + BB);          // [512]
    float* wcos = wpear + BB;                    // [512]
    float* wnmi = wcos + BB;                     // [512]

    k_main<<<dim3(BB), dim3(1024), 0, stream>>>(pred, targ, ip, wpear, wcos, wnum, wden, wnmi);
    k_combine<<<dim3(1), dim3(512), 0, stream>>>(wpear, wcos, wnum, wden, wnmi, ep, out);
}

// Round 5
// 208.306 us; speedup vs baseline: 1.2290x; 1.0306x over previous
//
#include <hip/hip_runtime.h>
#include <math.h>

#define BB 512
#define SS 16384
#define TPIF 6.28318530717958647692f

// float2 (b64) element pad: bank-pair = PD(e) mod 16. Verified conflict-free
// (4 lanes/pair = b64 minimum) for every stage access pattern with the
// j = t + c*1024 butterfly ordering: strides {1,4} with group jumps
// {64,256,1024,4096} all spread uniformly.
#define PD(i) ((i) + ((i) >> 4) + ((i) >> 8))
#define NPD 17472   // PD(16383)=17469 < 17472; 139.8 KB of LDS

// base-4 digit reversal of 14-bit index (7 digits)
__device__ __forceinline__ int digrev4(int n) {
    unsigned x = __brev((unsigned)n) >> (32 - 14);
    return (int)(((x & 0x1555u) << 1) | ((x >> 1) & 0x1555u));
}

// ---------------------------------------------------------------------------
// 64-VGPR design rule (R0-R4 evidence): allocator pins this kernel at 64
// VGPRs under every hint; any structure with >~50 live VGPRs spills to
// scratch. All FFT stages are single radix-4 butterflies (~30 live max).
// R5: complex-interleaved float2 LDS -> ds_*_b64, half the LDS instructions
// and half the address math of the split sre/sim layout; twiddle sincos is
// c-invariant (p = t & (Q-1)) for LOG2Q<=10 so it hoists to 1/stage.
// ---------------------------------------------------------------------------

// one radix-4 DIF stage: element stride Q, block 4Q, twiddle on outputs
template <int SGN, int LOG2Q>
__device__ __forceinline__ void stage_dif4(float2* sz, int t) {
    constexpr int Q = 1 << LOG2Q;
    const float sg = (float)SGN;
    #pragma unroll 2
    for (int c = 0; c < 4; ++c) {
        const int j = t + (c << 10);
        const int g = j >> LOG2Q;
        const int p = j & (Q - 1);
        const int e0 = (g << (LOG2Q + 2)) + p;
        const int i0 = PD(e0);
        const int i1 = PD(e0 + Q);
        const int i2 = PD(e0 + 2 * Q);
        const int i3 = PD(e0 + 3 * Q);
        float2 z0 = sz[i0], z1 = sz[i1], z2 = sz[i2], z3 = sz[i3];
        float t0r = z0.x + z2.x, t0i = z0.y + z2.y;
        float t1r = z0.x - z2.x, t1i = z0.y - z2.y;
        float t2r = z1.x + z3.x, t2i = z1.y + z3.y;
        float t3r = z1.x - z3.x, t3i = z1.y - z3.y;
        float b0r = t0r + t2r, b0i = t0i + t2i;
        float b2r = t0r - t2r, b2i = t0i - t2i;
        float b1r = t1r - sg * t3i, b1i = t1i + sg * t3r;
        float b3r = t1r + sg * t3i, b3i = t1i - sg * t3r;
        const float a = sg * (float)p * (1.0f / (4.0f * (float)Q));  // revolutions
        const float cb = __builtin_amdgcn_cosf(a);
        const float sb = __builtin_amdgcn_sinf(a);
        const float w2r = cb * cb - sb * sb, w2i = 2.0f * cb * sb;
        const float w3r = cb * w2r - sb * w2i, w3i = cb * w2i + sb * w2r;
        sz[i0] = make_float2(b0r, b0i);
        sz[i1] = make_float2(b1r * cb - b1i * sb,   b1r * sb + b1i * cb);
        sz[i2] = make_float2(b2r * w2r - b2i * w2i, b2r * w2i + b2i * w2r);
        sz[i3] = make_float2(b3r * w3r - b3i * w3i, b3r * w3i + b3i * w3r);
    }
    __syncthreads();
}

// one radix-4 DIT stage: element stride Q, block 4Q, twiddle on INPUTS
template <int SGN, int LOG2Q>
__device__ __forceinline__ void stage_dit4(float2* sz, int t) {
    constexpr int Q = 1 << LOG2Q;
    const float sg = (float)SGN;
    #pragma unroll 2
    for (int c = 0; c < 4; ++c) {
        const int j = t + (c << 10);
        const int g = j >> LOG2Q;
        const int p = j & (Q - 1);
        const int e0 = (g << (LOG2Q + 2)) + p;
        const int i0 = PD(e0);
        const int i1 = PD(e0 + Q);
        const int i2 = PD(e0 + 2 * Q);
        const int i3 = PD(e0 + 3 * Q);
        float2 z0 = sz[i0], z1 = sz[i1], z2 = sz[i2], z3 = sz[i3];
        const float a = sg * (float)p * (1.0f / (4.0f * (float)Q));  // revolutions
        const float cb = __builtin_amdgcn_cosf(a);
        const float sb = __builtin_amdgcn_sinf(a);
        const float w2r = cb * cb - sb * sb, w2i = 2.0f * cb * sb;
        const float w3r = cb * w2r - sb * w2i, w3i = cb * w2i + sb * w2r;
        float a1r = z1.x * cb - z1.y * sb,   a1i = z1.x * sb + z1.y * cb;
        float a2r = z2.x * w2r - z2.y * w2i, a2i = z2.x * w2i + z2.y * w2r;
        float a3r = z3.x * w3r - z3.y * w3i, a3i = z3.x * w3i + z3.y * w3r;
        float t0r = z0.x + a2r, t0i = z0.y + a2i;
        float t1r = z0.x - a2r, t1i = z0.y - a2i;
        float t2r = a1r + a3r, t2i = a1i + a3i;
        float t3r = a1r - a3r, t3i = a1i - a3i;
        sz[i0] = make_float2(t0r + t2r, t0i + t2i);
        sz[i2] = make_float2(t0r - t2r, t0i - t2i);
        sz[i1] = make_float2(t1r - sg * t3i, t1i + sg * t3r);
        sz[i3] = make_float2(t1r + sg * t3i, t1i - sg * t3r);
    }
    __syncthreads();
}

// ---------------------------------------------------------------------------
// Mega-kernel: one block per row does Pearson, MI, ONE forward FFT (shared by
// power spectrum AND phase correlation via the Hann spectral identity
// Zw[k] = 0.5 Z[k] - 0.25 (Z[k-1]+Z[k+1]), exact for the periodic window),
// and the inverse FFT for the phase-correlation argmax.
// ---------------------------------------------------------------------------
__global__ __launch_bounds__(1024, 4) void k_main(const float* __restrict__ pred,
                                                  const float* __restrict__ targ,
                                                  const int* __restrict__ ip,
                                                  float* __restrict__ wpear,
                                                  float* __restrict__ wcos,
                                                  double* __restrict__ wnum,
                                                  double* __restrict__ wden,
                                                  float* __restrict__ wnmi) {
    __shared__ float2 sz[NPD];
    __shared__ double dpart[16 * 5];
    __shared__ float fpart[16 * 4];
    __shared__ int   subhist[400];
    __shared__ float hxm[10], hym[10];
    __shared__ float mterm[128];
    __shared__ float sbounds[4];
    __shared__ float svalw[16];
    __shared__ int   sidxw[16];

    const int row = blockIdx.x;
    const int t = threadIdx.x;
    const int w = t >> 6;
    const int lane = t & 63;

    const float* xg = pred + (size_t)ip[0] * (size_t)BB * SS + (size_t)row * SS;
    const float* yg = targ + (size_t)row * SS;

    // ---- Load (float4) + Pearson sums (fp64) + min/max, streaming into LDS
    //      (sz = x + i y == FFT1 input, natural order).
    {
        const float4* xg4 = reinterpret_cast<const float4*>(xg);
        const float4* yg4 = reinterpret_cast<const float4*>(yg);
        double sx = 0, sy = 0, sxy = 0, sxx = 0, syy = 0;
        float xmn = 3.4e38f, xmx = -3.4e38f, ymn = 3.4e38f, ymx = -3.4e38f;
        #pragma unroll
        for (int m2 = 0; m2 < 4; ++m2) {
            int idx = t + (m2 << 10);          // float4 index
            float4 a = xg4[idx];
            float4 b = yg4[idx];
            int n0 = idx << 2;
            sz[PD(n0 + 0)] = make_float2(a.x, b.x);
            sz[PD(n0 + 1)] = make_float2(a.y, b.y);
            sz[PD(n0 + 2)] = make_float2(a.z, b.z);
            sz[PD(n0 + 3)] = make_float2(a.w, b.w);
            float av[4] = {a.x, a.y, a.z, a.w};
            float bv[4] = {b.x, b.y, b.z, b.w};
            #pragma unroll
            for (int c = 0; c < 4; ++c) {
                float aa = av[c], bb = bv[c];
                sx += (double)aa; sy += (double)bb;
                sxy += (double)aa * (double)bb;
                sxx += (double)aa * (double)aa;
                syy += (double)bb * (double)bb;
                xmn = fminf(xmn, aa); xmx = fmaxf(xmx, aa);
                ymn = fminf(ymn, bb); ymx = fmaxf(ymx, bb);
            }
        }
        #pragma unroll
        for (int o = 32; o > 0; o >>= 1) {
            sx += __shfl_down(sx, o, 64);  sy += __shfl_down(sy, o, 64);
            sxy += __shfl_down(sxy, o, 64);
            sxx += __shfl_down(sxx, o, 64); syy += __shfl_down(syy, o, 64);
            xmn = fminf(xmn, __shfl_down(xmn, o, 64));
            xmx = fmaxf(xmx, __shfl_down(xmx, o, 64));
            ymn = fminf(ymn, __shfl_down(ymn, o, 64));
            ymx = fmaxf(ymx, __shfl_down(ymx, o, 64));
        }
        if (lane == 0) {
            dpart[w*5+0] = sx; dpart[w*5+1] = sy; dpart[w*5+2] = sxy;
            dpart[w*5+3] = sxx; dpart[w*5+4] = syy;
            fpart[w*4+0] = xmn; fpart[w*4+1] = xmx; fpart[w*4+2] = ymn; fpart[w*4+3] = ymx;
        }
    }
    if (t < 400) subhist[t] = 0;
    __syncthreads();
    if (t == 0) {
        double v0=0,v1=0,v2=0,v3=0,v4=0;
        float b0=fpart[0], b1=fpart[1], b2=fpart[2], b3=fpart[3];
        for (int q = 0; q < 16; ++q) {
            v0 += dpart[q*5]; v1 += dpart[q*5+1]; v2 += dpart[q*5+2];
            v3 += dpart[q*5+3]; v4 += dpart[q*5+4];
            b0 = fminf(b0, fpart[q*4]);   b1 = fmaxf(b1, fpart[q*4+1]);
            b2 = fminf(b2, fpart[q*4+2]); b3 = fmaxf(b3, fpart[q*4+3]);
        }
        double N = (double)SS;
        double num = N * v2 - v0 * v1;
        double den = sqrt((N * v3 - v0 * v0) * (N * v4 - v1 * v1));
        wpear[row] = (float)(1.0 - num / den);
        sbounds[0] = b0; sbounds[1] = b1; sbounds[2] = b2; sbounds[3] = b3;
    }
    __syncthreads();

    // ---- MI histogram (x,y re-read from LDS; 4 sub-hists cut atomic contention)
    {
        const float x0 = sbounds[0], bwx = (sbounds[1] - x0) / 10.0f;
        const float y0 = sbounds[2], bwy = (sbounds[3] - y0) / 10.0f;
        int* hsub = subhist + ((t >> 6) & 3) * 100;
        #pragma unroll 2
        for (int m = 0; m < 16; ++m) {
            float2 v = sz[PD(t + (m << 10))];
            int ix = (int)((v.x - x0) / bwx); ix = min(max(ix, 0), 9);
            int iy = (int)((v.y - y0) / bwy); iy = min(max(iy, 0), 9);
            atomicAdd(&hsub[ix * 10 + iy], 1);
        }
    }
    __syncthreads();
    if (t < 100) subhist[t] = subhist[t] + subhist[100+t] + subhist[200+t] + subhist[300+t];
    __syncthreads();
    if (t < 10) {
        int s1 = 0, s2 = 0;
        for (int j = 0; j < 10; ++j) { s1 += subhist[t*10+j]; s2 += subhist[j*10+t]; }
        hxm[t] = (float)s1; hym[t] = (float)s2;
    }
    __syncthreads();
    {
        float term = 0.0f;
        if (t < 100) {
            const float denom = 8388608.0f, eps = 1e-8f;
            float pxy = (float)subhist[t] / denom;
            float px = hxm[t / 10] / denom, py = hym[t % 10] / denom;
            term = pxy * logf((pxy + eps) / (px * py + eps));
        }
        if (t < 128) mterm[t] = (t < 100) ? term : 0.0f;
    }
    __syncthreads();
    if (t == 0) {
        const float denom = 8388608.0f, eps = 1e-8f;
        float mi = 0.0f;
        for (int q = 0; q < 100; ++q) mi += mterm[q];
        float hxe = 0.0f, hye = 0.0f;
        for (int q = 0; q < 10; ++q) {
            float px = hxm[q] / denom, py = hym[q] / denom;
            hxe -= px * logf(px + eps);
            hye -= py * logf(py + eps);
        }
        wnmi[row] = mi / (0.5f * (hxe + hye));
    }
    __syncthreads();

    // ---- FFT1 (shared forward DIF, radix-4 x7): natural -> digit-reversed
    stage_dif4<-1, 12>(sz, t);
    stage_dif4<-1, 10>(sz, t);
    stage_dif4<-1,  8>(sz, t);
    stage_dif4<-1,  6>(sz, t);
    stage_dif4<-1,  4>(sz, t);
    stage_dif4<-1,  2>(sz, t);
    stage_dif4<-1,  0>(sz, t);

    // ---- Fused unpack: power sums (unwindowed) + phase-correlation C from
    //      the Hann-convolved spectrum. Reads before barrier, writes after
    //      (C parked in crv/civ: 16 VGPRs across ONE barrier; unroll 1 caps
    //      per-iteration pressure).
    {
        double anum = 0.0, aden = 0.0;
        float crv[8], civ[8];
        #pragma unroll 1
        for (int m = 0; m < 8; ++m) {
            int k = t + (m << 10);
            int km = (SS - k) & (SS - 1);
            int qa = digrev4(k), qb = digrev4(km);
            float2 za = sz[PD(qa)];
            float2 zb = sz[PD(qb)];
            float ar  = za.x, ai  = za.y;
            float cr0 = zb.x, ci0 = zb.y;
            // power spectrum terms (unwindowed)
            float xr = 0.5f * (ar + cr0), xi = 0.5f * (ai - ci0);
            float yr = 0.5f * (ai + ci0), yi = 0.5f * (cr0 - ar);
            float xp = xr * xr + xi * xi;
            float tp = yr * yr + yi * yi;
            anum += (double)fabsf(xp - tp);
            aden += (double)tp;
            // Hann conv: Zw[k] = 0.5 Z[k] - 0.25 (Z[k-1] + Z[k+1])
            float2 zap = sz[PD(digrev4((k + 1) & (SS - 1)))];
            float2 zam = sz[PD(digrev4((k - 1) & (SS - 1)))];
            float2 zbp = sz[PD(digrev4((km + 1) & (SS - 1)))];
            float2 zbm = sz[PD(digrev4((km - 1) & (SS - 1)))];
            float zwr = 0.5f * ar  - 0.25f * (zap.x + zam.x);
            float zwi = 0.5f * ai  - 0.25f * (zap.y + zam.y);
            float vwr = 0.5f * cr0 - 0.25f * (zbp.x + zbm.x);
            float vwi = 0.5f * ci0 - 0.25f * (zbp.y + zbm.y);
            // unpack windowed spectra Xw, Yw
            float xwr = 0.5f * (zwr + vwr), xwi = 0.5f * (zwi - vwi);
            float ywr = 0.5f * (zwi + vwi), ywi = 0.5f * (vwr - zwr);
            // C = Xw * conj(Yw) / |.|
            float cr = xwr * ywr + xwi * ywi;
            float ci = xwi * ywr - xwr * ywi;
            float mag = sqrtf(cr * cr + ci * ci);
            crv[m] = cr / mag; civ[m] = ci / mag;
        }
        float c8 = 0.0f;
        if (t == 0) {   // k = 8192 (self-conjugate)
            float2 z0 = sz[PD(digrev4(8192))];
            float2 zp = sz[PD(digrev4(8193))];
            float2 zm = sz[PD(digrev4(8191))];
            float ar = z0.x, ai = z0.y;
            anum += (double)fabsf(ar * ar - ai * ai);
            aden += (double)(ai * ai);
            float zwr = 0.5f * ar - 0.25f * (zp.x + zm.x);
            float zwi = 0.5f * ai - 0.25f * (zp.y + zm.y);
            float pr = zwr * zwi;          // Xw real, Yw real at Nyquist
            c8 = pr / fabsf(pr);
        }
        #pragma unroll
        for (int o = 32; o > 0; o >>= 1) {
            anum += __shfl_down(anum, o, 64);
            aden += __shfl_down(aden, o, 64);
        }
        if (lane == 0) { dpart[w*2] = anum; dpart[w*2+1] = aden; }
        __syncthreads();   // all spectrum reads done; safe to overwrite
        #pragma unroll
        for (int m = 0; m < 8; ++m) {
            int k = t + (m << 10);
            int km = (SS - k) & (SS - 1);
            int q = digrev4(k), q2 = digrev4(km);
            sz[PD(q)]  = make_float2(crv[m],  civ[m]);
            sz[PD(q2)] = make_float2(crv[m], -civ[m]);
        }
        if (t == 0) {
            sz[PD(digrev4(8192))] = make_float2(c8, 0.0f);
            double a = 0, b = 0;
            for (int q2_ = 0; q2_ < 16; ++q2_) { a += dpart[q2_*2]; b += dpart[q2_*2+1]; }
            wnum[row] = a; wden[row] = b;
        }
    }
    __syncthreads();

    // ---- FFT3 (inverse DIT, radix-4 x7): digit-reversed -> natural order
    stage_dit4<1,  0>(sz, t);
    stage_dit4<1,  2>(sz, t);
    stage_dit4<1,  4>(sz, t);
    stage_dit4<1,  6>(sz, t);
    stage_dit4<1,  8>(sz, t);
    stage_dit4<1, 10>(sz, t);
    stage_dit4<1, 12>(sz, t);

    // ---- argmax of real part (natural order), scalar running max (no arrays)
    {
        float bv = -3.4e38f; int bi = 0;
        #pragma unroll
        for (int m = 0; m < 16; ++m) {
            int n = t + (m << 10);
            float v = sz[PD(n)].x;
            if (v > bv) { bv = v; bi = n; }
        }
        #pragma unroll
        for (int o = 32; o > 0; o >>= 1) {
            float v2 = __shfl_down(bv, o, 64);
            int i2 = __shfl_down(bi, o, 64);
            if (v2 > bv || (v2 == bv && i2 < bi)) { bv = v2; bi = i2; }
        }
        if (lane == 0) { svalw[w] = bv; sidxw[w] = bi; }
    }
    __syncthreads();
    if (t == 0) {
        float bv = svalw[0]; int bi = sidxw[0];
        for (int q = 1; q < 16; ++q) {
            if (svalw[q] > bv || (svalw[q] == bv && sidxw[q] < bi)) { bv = svalw[q]; bi = sidxw[q]; }
        }
        wcos[row] = cosf(TPIF * (float)bi / 16384.0f);
    }
}

// ---------------------------------------------------------------------------
// Final combine (reads epoch on-device; graph-safe). Wave-shuffle reductions.
// ---------------------------------------------------------------------------
__global__ __launch_bounds__(512) void k_combine(const float* __restrict__ wpear,
                                                 const float* __restrict__ wcos,
                                                 const double* __restrict__ wnum,
                                                 const double* __restrict__ wden,
                                                 const float* __restrict__ wnmi,
                                                 const int* __restrict__ ep,
                                                 float* __restrict__ out) {
    __shared__ double dp[8 * 5];
    const int tid = threadIdx.x;
    const int w = tid >> 6, lane = tid & 63;
    double v0 = (double)wpear[tid], v1 = (double)wcos[tid];
    double v2 = wnum[tid], v3 = wden[tid], v4 = (double)wnmi[tid];
    #pragma unroll
    for (int o = 32; o > 0; o >>= 1) {
        v0 += __shfl_down(v0, o, 64); v1 += __shfl_down(v1, o, 64);
        v2 += __shfl_down(v2, o, 64); v3 += __shfl_down(v3, o, 64);
        v4 += __shfl_down(v4, o, 64);
    }
    if (lane == 0) {
        dp[w*5+0] = v0; dp[w*5+1] = v1; dp[w*5+2] = v2; dp[w*5+3] = v3; dp[w*5+4] = v4;
    }
    __syncthreads();
    if (tid == 0) {
        double s0=0,s1=0,s2=0,s3=0,s4=0;
        for (int q = 0; q < 8; ++q) {
            s0 += dp[q*5]; s1 += dp[q*5+1]; s2 += dp[q*5+2]; s3 += dp[q*5+3]; s4 += dp[q*5+4];
        }
        int epoch = ep[0];
        double loss = s0 / 512.0;
        if (epoch >= 400) {
            loss += 1.0 - s1 / 512.0;
            loss += s2 / s3;
        }
        if (epoch >= 700) {
            loss += 1.0 - s4 / 512.0;
        }
        out[0] = (float)loss;
    }
}

// ---------------------------------------------------------------------------
extern "C" void kernel_launch(void* const* d_in, const int* in_sizes, int n_in,
                              void* d_out, int out_size, void* d_ws, size_t ws_size,
                              hipStream_t stream) {
    const float* pred = (const float*)d_in[0];   // [2, 512, 16384] f32
    const float* targ = (const float*)d_in[1];   // [512, 16384] f32
    const int* ip = (const int*)d_in[2];         // scalar i
    const int* ep = (const int*)d_in[3];         // scalar epoch
    float* out = (float*)d_out;

    double* wnum = (double*)d_ws;                // [512]
    double* wden = wnum + BB;                    // [512]
    float* wpear = (float*)(wden + BB);          // [512]
    float* wcos = wpear + BB;                    // [512]
    float* wnmi = wcos + BB;                     // [512]

    k_main<<<dim3(BB), dim3(1024), 0, stream>>>(pred, targ, ip, wpear, wcos, wnum, wden, wnmi);
    k_combine<<<dim3(1), dim3(512), 0, stream>>>(wpear, wcos, wnum, wden, wnmi, ep, out);
}

// Round 7
// 199.299 us; speedup vs baseline: 1.2846x; 1.0452x over previous
//
#include <hip/hip_runtime.h>
#include <math.h>

#define BB 512
#define SS 16384
#define TPIF 6.28318530717958647692f

// float2 (b64) element pad. R5 post-mortem: measured "conflicts" are the
// structural b64 floor (4 lanes/bank-pair, ~3 counted cycles per wave access)
// -- layout is already optimal; do not re-tune.
#define PD(i) ((i) + ((i) >> 4) + ((i) >> 8))
#define NPD 17472   // PD(16383)=17469 < 17472; 139.8 KB of LDS

// mixed-radix [8,8,8,8,4] storage map: frequency k lives at element s(k) after
// DIF. k = k0 + 8k1 + 64k2 + 512k3 + 4096k4 (k0..k3 in [0,8), k4 in [0,4))
// s = k0*2048 + k1*256 + k2*32 + k3*4 + k4
// R6 post-mortem: stages store at PD(element); the unpack MUST read PD(smap),
// not smap -- the missing PD() was R6's correctness bug.
__device__ __forceinline__ int sp(int k) {
    int s = ((k & 7) << 11) + (((k >> 3) & 7) << 8) + (((k >> 6) & 7) << 5)
          + (((k >> 9) & 7) << 2) + ((k >> 12) & 3);
    return PD(s);
}

// ---------------------------------------------------------------------------
// 64-VGPR design rule (R0-R5 evidence): allocator pins this kernel at 64
// VGPRs; keep <=~45 live everywhere. Radix-8 stages: ONE butterfly live at a
// time (unroll 1 over the 2 butterflies/thread), outputs twiddled+stored
// sequentially. Incremental PD addressing: PD(e0+kQ) = PD(e0) + k*DQ exactly
// (p < Q keeps bit fields disjoint), DQ = Q + Q/16 + Q/256.
// ---------------------------------------------------------------------------

// radix-8 DIF stage (element stride Q, block 8Q, twiddle w^r on outputs)
template <int SGN, int LOG2Q>
__device__ __forceinline__ void stage_dif8(float2* sz, int t) {
    constexpr int Q = 1 << LOG2Q;
    constexpr int DQ = Q + (Q >> 4) + (Q >> 8);
    const float sg = (float)SGN;
    const float r2 = 0.70710678118654752f;
    #pragma unroll 1
    for (int c = 0; c < 2; ++c) {
        const int j = t + (c << 10);
        const int g = j >> LOG2Q;
        const int p = j & (Q - 1);
        const int i0 = PD((g << (LOG2Q + 3)) + p);
        int idx[8];
        #pragma unroll
        for (int k = 0; k < 8; ++k)
            idx[k] = (LOG2Q >= 4) ? (i0 + k * DQ) : (i0 + 4 * k + (k >> 2));  // Q=4 carry fix
        float2 z[8];
        #pragma unroll
        for (int k = 0; k < 8; ++k) z[k] = sz[idx[k]];
        // radix-2 split: a_k = z_k + z_{k+4}, b_k = z_k - z_{k+4}
        float2 a0, a1, a2, a3, b0, b1, b2, b3;
        a0 = make_float2(z[0].x + z[4].x, z[0].y + z[4].y);
        b0 = make_float2(z[0].x - z[4].x, z[0].y - z[4].y);
        a1 = make_float2(z[1].x + z[5].x, z[1].y + z[5].y);
        b1 = make_float2(z[1].x - z[5].x, z[1].y - z[5].y);
        a2 = make_float2(z[2].x + z[6].x, z[2].y + z[6].y);
        b2 = make_float2(z[2].x - z[6].x, z[2].y - z[6].y);
        a3 = make_float2(z[3].x + z[7].x, z[3].y + z[7].y);
        b3 = make_float2(z[3].x - z[7].x, z[3].y - z[7].y);
        // b_k *= W8^k, W8 = exp(sg*2pi*i/8)
        { float x = b1.x, y = b1.y; b1 = make_float2(r2 * (x - sg * y), r2 * (y + sg * x)); }
        { float x = b2.x, y = b2.y; b2 = make_float2(-sg * y, sg * x); }
        { float x = b3.x, y = b3.y; b3 = make_float2(-r2 * (x + sg * y), r2 * (sg * x - y)); }
        float2 o[8];
        {   // DFT4(a) -> even output slots 0,2,4,6
            float t0r = a0.x + a2.x, t0i = a0.y + a2.y;
            float t1r = a0.x - a2.x, t1i = a0.y - a2.y;
            float t2r = a1.x + a3.x, t2i = a1.y + a3.y;
            float t3r = a1.x - a3.x, t3i = a1.y - a3.y;
            o[0] = make_float2(t0r + t2r, t0i + t2i);
            o[4] = make_float2(t0r - t2r, t0i - t2i);
            o[2] = make_float2(t1r - sg * t3i, t1i + sg * t3r);
            o[6] = make_float2(t1r + sg * t3i, t1i - sg * t3r);
        }
        {   // DFT4(b') -> odd output slots 1,3,5,7
            float t0r = b0.x + b2.x, t0i = b0.y + b2.y;
            float t1r = b0.x - b2.x, t1i = b0.y - b2.y;
            float t2r = b1.x + b3.x, t2i = b1.y + b3.y;
            float t3r = b1.x - b3.x, t3i = b1.y - b3.y;
            o[1] = make_float2(t0r + t2r, t0i + t2i);
            o[5] = make_float2(t0r - t2r, t0i - t2i);
            o[3] = make_float2(t1r - sg * t3i, t1i + sg * t3r);
            o[7] = make_float2(t1r + sg * t3i, t1i - sg * t3r);
        }
        // output twiddles w^r, w = exp(sg*2pi*i*p/(8Q)); chained rotation
        const float arev = sg * (float)p * (1.0f / (8.0f * (float)Q));  // revolutions
        const float cb = __builtin_amdgcn_cosf(arev);
        const float sb = __builtin_amdgcn_sinf(arev);
        sz[idx[0]] = o[0];
        float wr = cb, wi = sb;
        #pragma unroll
        for (int r = 1; r < 8; ++r) {
            sz[idx[r]] = make_float2(o[r].x * wr - o[r].y * wi,
                                     o[r].x * wi + o[r].y * wr);
            float nr = wr * cb - wi * sb, ni = wr * sb + wi * cb;
            wr = nr; wi = ni;
        }
    }
    __syncthreads();
}

// radix-8 DIT stage (twiddle w^k on inputs; inverse uses SGN=+1)
template <int SGN, int LOG2Q>
__device__ __forceinline__ void stage_dit8(float2* sz, int t) {
    constexpr int Q = 1 << LOG2Q;
    constexpr int DQ = Q + (Q >> 4) + (Q >> 8);
    const float sg = (float)SGN;
    const float r2 = 0.70710678118654752f;
    #pragma unroll 1
    for (int c = 0; c < 2; ++c) {
        const int j = t + (c << 10);
        const int g = j >> LOG2Q;
        const int p = j & (Q - 1);
        const int i0 = PD((g << (LOG2Q + 3)) + p);
        int idx[8];
        #pragma unroll
        for (int k = 0; k < 8; ++k)
            idx[k] = (LOG2Q >= 4) ? (i0 + k * DQ) : (i0 + 4 * k + (k >> 2));
        const float arev = sg * (float)p * (1.0f / (8.0f * (float)Q));  // revolutions
        const float cb = __builtin_amdgcn_cosf(arev);
        const float sb = __builtin_amdgcn_sinf(arev);
        float2 z[8];
        z[0] = sz[idx[0]];
        float wr = cb, wi = sb;
        #pragma unroll
        for (int k = 1; k < 8; ++k) {
            float2 v = sz[idx[k]];
            z[k] = make_float2(v.x * wr - v.y * wi, v.x * wi + v.y * wr);
            float nr = wr * cb - wi * sb, ni = wr * sb + wi * cb;
            wr = nr; wi = ni;
        }
        // U = IDFT4(z0,z2,z4,z6), V = IDFT4(z1,z3,z5,z7)
        float2 U0, U1, U2, U3, V0, V1, V2, V3;
        {
            float t0r = z[0].x + z[4].x, t0i = z[0].y + z[4].y;
            float t1r = z[0].x - z[4].x, t1i = z[0].y - z[4].y;
            float t2r = z[2].x + z[6].x, t2i = z[2].y + z[6].y;
            float t3r = z[2].x - z[6].x, t3i = z[2].y - z[6].y;
            U0 = make_float2(t0r + t2r, t0i + t2i);
            U2 = make_float2(t0r - t2r, t0i - t2i);
            U1 = make_float2(t1r - sg * t3i, t1i + sg * t3r);
            U3 = make_float2(t1r + sg * t3i, t1i - sg * t3r);
        }
        {
            float t0r = z[1].x + z[5].x, t0i = z[1].y + z[5].y;
            float t1r = z[1].x - z[5].x, t1i = z[1].y - z[5].y;
            float t2r = z[3].x + z[7].x, t2i = z[3].y + z[7].y;
            float t3r = z[3].x - z[7].x, t3i = z[3].y - z[7].y;
            V0 = make_float2(t0r + t2r, t0i + t2i);
            V2 = make_float2(t0r - t2r, t0i - t2i);
            V1 = make_float2(t1r - sg * t3i, t1i + sg * t3r);
            V3 = make_float2(t1r + sg * t3i, t1i - sg * t3r);
        }
        // out[n] = U[n] + W8^n V[n]; out[n+4] = U[n] - W8^n V[n]
        {
            float2 tw = V0;
            sz[idx[0]] = make_float2(U0.x + tw.x, U0.y + tw.y);
            sz[idx[4]] = make_float2(U0.x - tw.x, U0.y - tw.y);
        }
        {
            float2 tw = make_float2(r2 * (V1.x - sg * V1.y), r2 * (V1.y + sg * V1.x));
            sz[idx[1]] = make_float2(U1.x + tw.x, U1.y + tw.y);
            sz[idx[5]] = make_float2(U1.x - tw.x, U1.y - tw.y);
        }
        {
            float2 tw = make_float2(-sg * V2.y, sg * V2.x);
            sz[idx[2]] = make_float2(U2.x + tw.x, U2.y + tw.y);
            sz[idx[6]] = make_float2(U2.x - tw.x, U2.y - tw.y);
        }
        {
            float2 tw = make_float2(-r2 * (V3.x + sg * V3.y), r2 * (sg * V3.x - V3.y));
            sz[idx[3]] = make_float2(U3.x + tw.x, U3.y + tw.y);
            sz[idx[7]] = make_float2(U3.x - tw.x, U3.y - tw.y);
        }
    }
    __syncthreads();
}

// twiddle-free radix-4 stage on contiguous quads (Q=1): DIF-last / DIT-first.
// The no-twiddle radix-4 output assignment is identical for DIF and DIT.
template <int SGN>
__device__ __forceinline__ void stage_nt4(float2* sz, int t) {
    const float sg = (float)SGN;
    #pragma unroll 1
    for (int c = 0; c < 4; ++c) {
        const int j = t + (c << 10);
        const int i0 = 4 * j + (j >> 2) + (j >> 6);   // PD(4j); PD(4j+k)=i0+k (no carry)
        float2 z0 = sz[i0], z1 = sz[i0 + 1], z2 = sz[i0 + 2], z3 = sz[i0 + 3];
        float t0r = z0.x + z2.x, t0i = z0.y + z2.y;
        float t1r = z0.x - z2.x, t1i = z0.y - z2.y;
        float t2r = z1.x + z3.x, t2i = z1.y + z3.y;
        float t3r = z1.x - z3.x, t3i = z1.y - z3.y;
        sz[i0]     = make_float2(t0r + t2r, t0i + t2i);
        sz[i0 + 2] = make_float2(t0r - t2r, t0i - t2i);
        sz[i0 + 1] = make_float2(t1r - sg * t3i, t1i + sg * t3r);
        sz[i0 + 3] = make_float2(t1r + sg * t3i, t1i - sg * t3r);
    }
    __syncthreads();
}

// ---------------------------------------------------------------------------
// Mega-kernel: one block per row does Pearson, MI, ONE forward FFT (shared by
// power spectrum AND phase correlation via the Hann spectral identity
// Zw[k] = 0.5 Z[k] - 0.25 (Z[k-1]+Z[k+1]), exact for the periodic window),
// and the inverse FFT for the phase-correlation argmax.
// ---------------------------------------------------------------------------
__global__ __launch_bounds__(1024, 4) void k_main(const float* __restrict__ pred,
                                                  const float* __restrict__ targ,
                                                  const int* __restrict__ ip,
                                                  float* __restrict__ wpear,
                                                  float* __restrict__ wcos,
                                                  double* __restrict__ wnum,
                                                  double* __restrict__ wden,
                                                  float* __restrict__ wnmi) {
    __shared__ float2 sz[NPD];
    __shared__ double dpart[16 * 5];
    __shared__ float fpart[16 * 4];
    __shared__ int   subhist[400];
    __shared__ float hxm[10], hym[10];
    __shared__ float mterm[128];
    __shared__ float sbounds[4];
    __shared__ float svalw[16];
    __shared__ int   sidxw[16];

    const int row = blockIdx.x;
    const int t = threadIdx.x;
    const int w = t >> 6;
    const int lane = t & 63;

    const float* xg = pred + (size_t)ip[0] * (size_t)BB * SS + (size_t)row * SS;
    const float* yg = targ + (size_t)row * SS;

    // ---- Load (float4) + Pearson sums (fp64) + min/max, streaming into LDS
    //      (sz = x + i y == FFT1 input, natural order).
    {
        const float4* xg4 = reinterpret_cast<const float4*>(xg);
        const float4* yg4 = reinterpret_cast<const float4*>(yg);
        double sx = 0, sy = 0, sxy = 0, sxx = 0, syy = 0;
        float xmn = 3.4e38f, xmx = -3.4e38f, ymn = 3.4e38f, ymx = -3.4e38f;
        #pragma unroll
        for (int m2 = 0; m2 < 4; ++m2) {
            int idx = t + (m2 << 10);          // float4 index
            float4 a = xg4[idx];
            float4 b = yg4[idx];
            int n0 = idx << 2;
            sz[PD(n0 + 0)] = make_float2(a.x, b.x);
            sz[PD(n0 + 1)] = make_float2(a.y, b.y);
            sz[PD(n0 + 2)] = make_float2(a.z, b.z);
            sz[PD(n0 + 3)] = make_float2(a.w, b.w);
            float av[4] = {a.x, a.y, a.z, a.w};
            float bv[4] = {b.x, b.y, b.z, b.w};
            #pragma unroll
            for (int c = 0; c < 4; ++c) {
                float aa = av[c], bb = bv[c];
                sx += (double)aa; sy += (double)bb;
                sxy += (double)aa * (double)bb;
                sxx += (double)aa * (double)aa;
                syy += (double)bb * (double)bb;
                xmn = fminf(xmn, aa); xmx = fmaxf(xmx, aa);
                ymn = fminf(ymn, bb); ymx = fmaxf(ymx, bb);
            }
        }
        #pragma unroll
        for (int o = 32; o > 0; o >>= 1) {
            sx += __shfl_down(sx, o, 64);  sy += __shfl_down(sy, o, 64);
            sxy += __shfl_down(sxy, o, 64);
            sxx += __shfl_down(sxx, o, 64); syy += __shfl_down(syy, o, 64);
            xmn = fminf(xmn, __shfl_down(xmn, o, 64));
            xmx = fmaxf(xmx, __shfl_down(xmx, o, 64));
            ymn = fminf(ymn, __shfl_down(ymn, o, 64));
            ymx = fmaxf(ymx, __shfl_down(ymx, o, 64));
        }
        if (lane == 0) {
            dpart[w*5+0] = sx; dpart[w*5+1] = sy; dpart[w*5+2] = sxy;
            dpart[w*5+3] = sxx; dpart[w*5+4] = syy;
            fpart[w*4+0] = xmn; fpart[w*4+1] = xmx; fpart[w*4+2] = ymn; fpart[w*4+3] = ymx;
        }
    }
    if (t < 400) subhist[t] = 0;
    __syncthreads();
    if (t == 0) {
        double v0=0,v1=0,v2=0,v3=0,v4=0;
        float b0=fpart[0], b1=fpart[1], b2=fpart[2], b3=fpart[3];
        for (int q = 0; q < 16; ++q) {
            v0 += dpart[q*5]; v1 += dpart[q*5+1]; v2 += dpart[q*5+2];
            v3 += dpart[q*5+3]; v4 += dpart[q*5+4];
            b0 = fminf(b0, fpart[q*4]);   b1 = fmaxf(b1, fpart[q*4+1]);
            b2 = fminf(b2, fpart[q*4+2]); b3 = fmaxf(b3, fpart[q*4+3]);
        }
        double N = (double)SS;
        double num = N * v2 - v0 * v1;
        double den = sqrt((N * v3 - v0 * v0) * (N * v4 - v1 * v1));
        wpear[row] = (float)(1.0 - num / den);
        sbounds[0] = b0; sbounds[1] = b1; sbounds[2] = b2; sbounds[3] = b3;
    }
    __syncthreads();

    // ---- MI histogram (x,y re-read from LDS; 4 sub-hists cut atomic contention)
    {
        const float x0 = sbounds[0], bwx = (sbounds[1] - x0) / 10.0f;
        const float y0 = sbounds[2], bwy = (sbounds[3] - y0) / 10.0f;
        int* hsub = subhist + ((t >> 6) & 3) * 100;
        #pragma unroll 2
        for (int m = 0; m < 16; ++m) {
            float2 v = sz[PD(t + (m << 10))];
            int ix = (int)((v.x - x0) / bwx); ix = min(max(ix, 0), 9);
            int iy = (int)((v.y - y0) / bwy); iy = min(max(iy, 0), 9);
            atomicAdd(&hsub[ix * 10 + iy], 1);
        }
    }
    __syncthreads();
    if (t < 100) subhist[t] = subhist[t] + subhist[100+t] + subhist[200+t] + subhist[300+t];
    __syncthreads();
    if (t < 10) {
        int s1 = 0, s2 = 0;
        for (int j = 0; j < 10; ++j) { s1 += subhist[t*10+j]; s2 += subhist[j*10+t]; }
        hxm[t] = (float)s1; hym[t] = (float)s2;
    }
    __syncthreads();
    {
        float term = 0.0f;
        if (t < 100) {
            const float denom = 8388608.0f, eps = 1e-8f;
            float pxy = (float)subhist[t] / denom;
            float px = hxm[t / 10] / denom, py = hym[t % 10] / denom;
            term = pxy * logf((pxy + eps) / (px * py + eps));
        }
        if (t < 128) mterm[t] = (t < 100) ? term : 0.0f;
    }
    __syncthreads();
    if (t == 0) {
        const float denom = 8388608.0f, eps = 1e-8f;
        float mi = 0.0f;
        for (int q = 0; q < 100; ++q) mi += mterm[q];
        float hxe = 0.0f, hye = 0.0f;
        for (int q = 0; q < 10; ++q) {
            float px = hxm[q] / denom, py = hym[q] / denom;
            hxe -= px * logf(px + eps);
            hye -= py * logf(py + eps);
        }
        wnmi[row] = mi / (0.5f * (hxe + hye));
    }
    __syncthreads();

    // ---- FFT1 (shared forward DIF, radix 8x4 then 4): natural -> s-order
    stage_dif8<-1, 11>(sz, t);   // Q=2048
    stage_dif8<-1,  8>(sz, t);   // Q=256
    stage_dif8<-1,  5>(sz, t);   // Q=32
    stage_dif8<-1,  2>(sz, t);   // Q=4
    stage_nt4<-1>(sz, t);        // Q=1, twiddle-free

    // ---- Fused unpack: power sums (unwindowed) + phase-correlation C from
    //      the Hann-convolved spectrum. Reads before barrier, writes after
    //      (C parked in crv/civ: 16 VGPRs across ONE barrier).
    {
        double anum = 0.0, aden = 0.0;
        float crv[8], civ[8];
        #pragma unroll 1
        for (int m = 0; m < 8; ++m) {
            int k = t + (m << 10);
            int km = (SS - k) & (SS - 1);
            float2 za = sz[sp(k)];
            float2 zb = sz[sp(km)];
            float ar  = za.x, ai  = za.y;
            float cr0 = zb.x, ci0 = zb.y;
            // power spectrum terms (unwindowed)
            float xr = 0.5f * (ar + cr0), xi = 0.5f * (ai - ci0);
            float yr = 0.5f * (ai + ci0), yi = 0.5f * (cr0 - ar);
            float xp = xr * xr + xi * xi;
            float tp = yr * yr + yi * yi;
            anum += (double)fabsf(xp - tp);
            aden += (double)tp;
            // Hann conv: Zw[k] = 0.5 Z[k] - 0.25 (Z[k-1] + Z[k+1])
            float2 zap = sz[sp((k + 1) & (SS - 1))];
            float2 zam = sz[sp((k - 1) & (SS - 1))];
            float2 zbp = sz[sp((km + 1) & (SS - 1))];
            float2 zbm = sz[sp((km - 1) & (SS - 1))];
            float zwr = 0.5f * ar  - 0.25f * (zap.x + zam.x);
            float zwi = 0.5f * ai  - 0.25f * (zap.y + zam.y);
            float vwr = 0.5f * cr0 - 0.25f * (zbp.x + zbm.x);
            float vwi = 0.5f * ci0 - 0.25f * (zbp.y + zbm.y);
            // unpack windowed spectra Xw, Yw
            float xwr = 0.5f * (zwr + vwr), xwi = 0.5f * (zwi - vwi);
            float ywr = 0.5f * (zwi + vwi), ywi = 0.5f * (vwr - zwr);
            // C = Xw * conj(Yw) / |.|
            float cr = xwr * ywr + xwi * ywi;
            float ci = xwi * ywr - xwr * ywi;
            float mag = sqrtf(cr * cr + ci * ci);
            crv[m] = cr / mag; civ[m] = ci / mag;
        }
        float c8 = 0.0f;
        if (t == 0) {   // k = 8192 (self-conjugate)
            float2 z0 = sz[sp(8192)];
            float2 zp = sz[sp(8193)];
            float2 zm = sz[sp(8191)];
            float ar = z0.x, ai = z0.y;
            anum += (double)fabsf(ar * ar - ai * ai);
            aden += (double)(ai * ai);
            float zwr = 0.5f * ar - 0.25f * (zp.x + zm.x);
            float zwi = 0.5f * ai - 0.25f * (zp.y + zm.y);
            float pr = zwr * zwi;          // Xw real, Yw real at Nyquist
            c8 = pr / fabsf(pr);
        }
        #pragma unroll
        for (int o = 32; o > 0; o >>= 1) {
            anum += __shfl_down(anum, o, 64);
            aden += __shfl_down(aden, o, 64);
        }
        if (lane == 0) { dpart[w*2] = anum; dpart[w*2+1] = aden; }
        __syncthreads();   // all spectrum reads done; safe to overwrite
        #pragma unroll
        for (int m = 0; m < 8; ++m) {
            int k = t + (m << 10);
            int km = (SS - k) & (SS - 1);
            sz[sp(k)]  = make_float2(crv[m],  civ[m]);
            sz[sp(km)] = make_float2(crv[m], -civ[m]);
        }
        if (t == 0) {
            sz[sp(8192)] = make_float2(c8, 0.0f);
            double a = 0, b = 0;
            for (int q2_ = 0; q2_ < 16; ++q2_) { a += dpart[q2_*2]; b += dpart[q2_*2+1]; }
            wnum[row] = a; wden[row] = b;
        }
    }
    __syncthreads();

    // ---- FFT3 (inverse DIT, mirrored stages): s-order -> natural
    stage_nt4<1>(sz, t);         // Q=1, twiddle-free
    stage_dit8<1,  2>(sz, t);    // Q=4
    stage_dit8<1,  5>(sz, t);    // Q=32
    stage_dit8<1,  8>(sz, t);    // Q=256
    stage_dit8<1, 11>(sz, t);    // Q=2048

    // ---- argmax of real part (natural order), scalar running max
    {
        float bv = -3.4e38f; int bi = 0;
        #pragma unroll
        for (int m = 0; m < 16; ++m) {
            int n = t + (m << 10);
            float v = sz[PD(n)].x;
            if (v > bv) { bv = v; bi = n; }
        }
        #pragma unroll
        for (int o = 32; o > 0; o >>= 1) {
            float v2 = __shfl_down(bv, o, 64);
            int i2 = __shfl_down(bi, o, 64);
            if (v2 > bv || (v2 == bv && i2 < bi)) { bv = v2; bi = i2; }
        }
        if (lane == 0) { svalw[w] = bv; sidxw[w] = bi; }
    }
    __syncthreads();
    if (t == 0) {
        float bv = svalw[0]; int bi = sidxw[0];
        for (int q = 1; q < 16; ++q) {
            if (svalw[q] > bv || (svalw[q] == bv && sidxw[q] < bi)) { bv = svalw[q]; bi = sidxw[q]; }
        }
        wcos[row] = cosf(TPIF * (float)bi / 16384.0f);
    }
}

// ---------------------------------------------------------------------------
// Final combine (reads epoch on-device; graph-safe). Wave-shuffle reductions.
// ---------------------------------------------------------------------------
__global__ __launch_bounds__(512) void k_combine(const float* __restrict__ wpear,
                                                 const float* __restrict__ wcos,
                                                 const double* __restrict__ wnum,
                                                 const double* __restrict__ wden,
                                                 const float* __restrict__ wnmi,
                                                 const int* __restrict__ ep,
                                                 float* __restrict__ out) {
    __shared__ double dp[8 * 5];
    const int tid = threadIdx.x;
    const int w = tid >> 6, lane = tid & 63;
    double v0 = (double)wpear[tid], v1 = (double)wcos[tid];
    double v2 = wnum[tid], v3 = wden[tid], v4 = (double)wnmi[tid];
    #pragma unroll
    for (int o = 32; o > 0; o >>= 1) {
        v0 += __shfl_down(v0, o, 64); v1 += __shfl_down(v1, o, 64);
        v2 += __shfl_down(v2, o, 64); v3 += __shfl_down(v3, o, 64);
        v4 += __shfl_down(v4, o, 64);
    }
    if (lane == 0) {
        dp[w*5+0] = v0; dp[w*5+1] = v1; dp[w*5+2] = v2; dp[w*5+3] = v3; dp[w*5+4] = v4;
    }
    __syncthreads();
    if (tid == 0) {
        double s0=0,s1=0,s2=0,s3=0,s4=0;
        for (int q = 0; q < 8; ++q) {
            s0 += dp[q*5]; s1 += dp[q*5+1]; s2 += dp[q*5+2]; s3 += dp[q*5+3]; s4 += dp[q*5+4];
        }
        int epoch = ep[0];
        double loss = s0 / 512.0;
        if (epoch >= 400) {
            loss += 1.0 - s1 / 512.0;
            loss += s2 / s3;
        }
        if (epoch >= 700) {
            loss += 1.0 - s4 / 512.0;
        }
        out[0] = (float)loss;
    }
}

// ---------------------------------------------------------------------------
extern "C" void kernel_launch(void* const* d_in, const int* in_sizes, int n_in,
                              void* d_out, int out_size, void* d_ws, size_t ws_size,
                              hipStream_t stream) {
    const float* pred = (const float*)d_in[0];   // [2, 512, 16384] f32
    const float* targ = (const float*)d_in[1];   // [512, 16384] f32
    const int* ip = (const int*)d_in[2];         // scalar i
    const int* ep = (const int*)d_in[3];         // scalar epoch
    float* out = (float*)d_out;

    double* wnum = (double*)d_ws;                // [512]
    double* wden = wnum + BB;                    // [512]
    float* wpear = (float*)(wden + BB);          // [512]
    float* wcos = wpear + BB;                    // [512]
    float* wnmi = wcos + BB;                     // [512]

    k_main<<<dim3(BB), dim3(1024), 0, stream>>>(pred, targ, ip, wpear, wcos, wnum, wden, wnmi);
    k_combine<<<dim3(1), dim3(512), 0, stream>>>(wpear, wcos, wnum, wden, wnmi, ep, out);
}

// Round 9
// 190.293 us; speedup vs baseline: 1.3454x; 1.0473x over previous
//
#include <hip/hip_runtime.h>
#include <math.h>

#define BB 512
#define SS 16384
#define TPIF 6.28318530717958647692f

// float2 (b64) element pad. Measured "conflicts" are the structural b64 floor
// (4 lanes/bank-pair); layout already optimal -- do not re-tune.
#define PD(i) ((i) + ((i) >> 4) + ((i) >> 8))
#define NPD 17472   // PD(16383)=17469 < 17472; 139.8 KB of LDS
#define BBASE 8200  // 8K-IFFT region base; C natural occupies slots [0..8192]

// mixed-radix [8,8,8,8,4] storage map for the 16K forward DIF: frequency k
// lives at element s(k). R6 lesson: always wrap with PD().
__device__ __forceinline__ int sp(int k) {
    int s = ((k & 7) << 11) + (((k >> 3) & 7) << 8) + (((k >> 6) & 7) << 5)
          + (((k >> 9) & 7) << 2) + ((k >> 12) & 3);
    return PD(s);
}

// ---------------------------------------------------------------------------
// 64-VGPR design rule (R0-R7 evidence): allocator pins this kernel at 64
// VGPRs; keep <=~45 live everywhere (radix-8 = 16 data VGPRs + temps, OK).
// Incremental PD addressing: PD(e0+k*Q) = PD(e0) + k*DQ where bit fields are
// disjoint; Q=128 needs the extra (k>>1) carry term (derived, see stage8k).
// ---------------------------------------------------------------------------

// 16K radix-8 DIF stage (2 butterflies/thread), twiddle w^r on outputs
template <int SGN, int LOG2Q>
__device__ __forceinline__ void stage_dif8(float2* sz, int t) {
    constexpr int Q = 1 << LOG2Q;
    constexpr int DQ = Q + (Q >> 4) + (Q >> 8);
    const float sg = (float)SGN;
    const float r2 = 0.70710678118654752f;
    #pragma unroll 1
    for (int c = 0; c < 2; ++c) {
        const int j = t + (c << 10);
        const int g = j >> LOG2Q;
        const int p = j & (Q - 1);
        const int i0 = PD((g << (LOG2Q + 3)) + p);
        int idx[8];
        #pragma unroll
        for (int k = 0; k < 8; ++k)
            idx[k] = (LOG2Q >= 4) ? (i0 + k * DQ) : (i0 + 4 * k + (k >> 2));  // Q=4 carry fix
        float2 z[8];
        #pragma unroll
        for (int k = 0; k < 8; ++k) z[k] = sz[idx[k]];
        float2 a0, a1, a2, a3, b0, b1, b2, b3;
        a0 = make_float2(z[0].x + z[4].x, z[0].y + z[4].y);
        b0 = make_float2(z[0].x - z[4].x, z[0].y - z[4].y);
        a1 = make_float2(z[1].x + z[5].x, z[1].y + z[5].y);
        b1 = make_float2(z[1].x - z[5].x, z[1].y - z[5].y);
        a2 = make_float2(z[2].x + z[6].x, z[2].y + z[6].y);
        b2 = make_float2(z[2].x - z[6].x, z[2].y - z[6].y);
        a3 = make_float2(z[3].x + z[7].x, z[3].y + z[7].y);
        b3 = make_float2(z[3].x - z[7].x, z[3].y - z[7].y);
        { float x = b1.x, y = b1.y; b1 = make_float2(r2 * (x - sg * y), r2 * (y + sg * x)); }
        { float x = b2.x, y = b2.y; b2 = make_float2(-sg * y, sg * x); }
        { float x = b3.x, y = b3.y; b3 = make_float2(-r2 * (x + sg * y), r2 * (sg * x - y)); }
        float2 o[8];
        {
            float t0r = a0.x + a2.x, t0i = a0.y + a2.y;
            float t1r = a0.x - a2.x, t1i = a0.y - a2.y;
            float t2r = a1.x + a3.x, t2i = a1.y + a3.y;
            float t3r = a1.x - a3.x, t3i = a1.y - a3.y;
            o[0] = make_float2(t0r + t2r, t0i + t2i);
            o[4] = make_float2(t0r - t2r, t0i - t2i);
            o[2] = make_float2(t1r - sg * t3i, t1i + sg * t3r);
            o[6] = make_float2(t1r + sg * t3i, t1i - sg * t3r);
        }
        {
            float t0r = b0.x + b2.x, t0i = b0.y + b2.y;
            float t1r = b0.x - b2.x, t1i = b0.y - b2.y;
            float t2r = b1.x + b3.x, t2i = b1.y + b3.y;
            float t3r = b1.x - b3.x, t3i = b1.y - b3.y;
            o[1] = make_float2(t0r + t2r, t0i + t2i);
            o[5] = make_float2(t0r - t2r, t0i - t2i);
            o[3] = make_float2(t1r - sg * t3i, t1i + sg * t3r);
            o[7] = make_float2(t1r + sg * t3i, t1i - sg * t3r);
        }
        const float arev = sg * (float)p * (1.0f / (8.0f * (float)Q));  // revolutions
        const float cb = __builtin_amdgcn_cosf(arev);
        const float sb = __builtin_amdgcn_sinf(arev);
        sz[idx[0]] = o[0];
        float wr = cb, wi = sb;
        #pragma unroll
        for (int r = 1; r < 8; ++r) {
            sz[idx[r]] = make_float2(o[r].x * wr - o[r].y * wi,
                                     o[r].x * wi + o[r].y * wr);
            float nr = wr * cb - wi * sb, ni = wr * sb + wi * cb;
            wr = nr; wi = ni;
        }
    }
    __syncthreads();
}

// 16K twiddle-free radix-4 stage on contiguous quads (Q=1, 4/thread)
template <int SGN>
__device__ __forceinline__ void stage_nt4(float2* sz, int t) {
    const float sg = (float)SGN;
    #pragma unroll 1
    for (int c = 0; c < 4; ++c) {
        const int j = t + (c << 10);
        const int i0 = 4 * j + (j >> 2) + (j >> 6);   // PD(4j); PD(4j+k)=i0+k
        float2 z0 = sz[i0], z1 = sz[i0 + 1], z2 = sz[i0 + 2], z3 = sz[i0 + 3];
        float t0r = z0.x + z2.x, t0i = z0.y + z2.y;
        float t1r = z0.x - z2.x, t1i = z0.y - z2.y;
        float t2r = z1.x + z3.x, t2i = z1.y + z3.y;
        float t3r = z1.x - z3.x, t3i = z1.y - z3.y;
        sz[i0]     = make_float2(t0r + t2r, t0i + t2i);
        sz[i0 + 2] = make_float2(t0r - t2r, t0i - t2i);
        sz[i0 + 1] = make_float2(t1r - sg * t3i, t1i + sg * t3r);
        sz[i0 + 3] = make_float2(t1r + sg * t3i, t1i - sg * t3r);
    }
    __syncthreads();
}

// ---------------------------------------------------------------------------
// 8K (half-size, real-output) inverse chain stages, region base bz = sz+BBASE.
// Chain: r8 Q=1024, r8 Q=128, r8 Q=16, r4 Q=4, r4 Q=1 (8*8*8*4*4 = 8192).
// Output map: time-lag n at slot (n&7)*1024 + ((n>>3)&7)*128 + ((n>>6)&7)*16
//             + ((n>>9)&3)*4 + (n>>11).
// PD increments: Q=1024 -> 1092 exact; Q=16 -> 17 exact; Q=128 -> 136k+(k>>1)
// (the 128k>>8 = k>>1 carry, derived; p<128 never crosses a 256 boundary).
// ---------------------------------------------------------------------------
template <int SGN, int LOG2Q>
__device__ __forceinline__ void stage8k_dif8(float2* bz, int t) {
    constexpr int Q = 1 << LOG2Q;
    constexpr int DQ = Q + (Q >> 4) + (Q >> 8);
    constexpr int CORR = (LOG2Q == 7) ? 1 : 0;
    const float sg = (float)SGN;
    const float r2 = 0.70710678118654752f;
    const int g = t >> LOG2Q;                 // 1024 butterflies = 1/thread
    const int p = t & (Q - 1);
    const int i0 = PD((g << (LOG2Q + 3)) + p);
    int idx[8];
    #pragma unroll
    for (int k = 0; k < 8; ++k) idx[k] = i0 + k * DQ + CORR * (k >> 1);
    float2 z[8];
    #pragma unroll
    for (int k = 0; k < 8; ++k) z[k] = bz[idx[k]];
    float2 a0, a1, a2, a3, b0, b1, b2, b3;
    a0 = make_float2(z[0].x + z[4].x, z[0].y + z[4].y);
    b0 = make_float2(z[0].x - z[4].x, z[0].y - z[4].y);
    a1 = make_float2(z[1].x + z[5].x, z[1].y + z[5].y);
    b1 = make_float2(z[1].x - z[5].x, z[1].y - z[5].y);
    a2 = make_float2(z[2].x + z[6].x, z[2].y + z[6].y);
    b2 = make_float2(z[2].x - z[6].x, z[2].y - z[6].y);
    a3 = make_float2(z[3].x + z[7].x, z[3].y + z[7].y);
    b3 = make_float2(z[3].x - z[7].x, z[3].y - z[7].y);
    { float x = b1.x, y = b1.y; b1 = make_float2(r2 * (x - sg * y), r2 * (y + sg * x)); }
    { float x = b2.x, y = b2.y; b2 = make_float2(-sg * y, sg * x); }
    { float x = b3.x, y = b3.y; b3 = make_float2(-r2 * (x + sg * y), r2 * (sg * x - y)); }
    float2 o[8];
    {
        float t0r = a0.x + a2.x, t0i = a0.y + a2.y;
        float t1r = a0.x - a2.x, t1i = a0.y - a2.y;
        float t2r = a1.x + a3.x, t2i = a1.y + a3.y;
        float t3r = a1.x - a3.x, t3i = a1.y - a3.y;
        o[0] = make_float2(t0r + t2r, t0i + t2i);
        o[4] = make_float2(t0r - t2r, t0i - t2i);
        o[2] = make_float2(t1r - sg * t3i, t1i + sg * t3r);
        o[6] = make_float2(t1r + sg * t3i, t1i - sg * t3r);
    }
    {
        float t0r = b0.x + b2.x, t0i = b0.y + b2.y;
        float t1r = b0.x - b2.x, t1i = b0.y - b2.y;
        float t2r = b1.x + b3.x, t2i = b1.y + b3.y;
        float t3r = b1.x - b3.x, t3i = b1.y - b3.y;
        o[1] = make_float2(t0r + t2r, t0i + t2i);
        o[5] = make_float2(t0r - t2r, t0i - t2i);
        o[3] = make_float2(t1r - sg * t3i, t1i + sg * t3r);
        o[7] = make_float2(t1r + sg * t3i, t1i - sg * t3r);
    }
    const float arev = sg * (float)p * (1.0f / (8.0f * (float)Q));  // revolutions
    const float cb = __builtin_amdgcn_cosf(arev);
    const float sb = __builtin_amdgcn_sinf(arev);
    bz[idx[0]] = o[0];
    float wr = cb, wi = sb;
    #pragma unroll
    for (int r = 1; r < 8; ++r) {
        bz[idx[r]] = make_float2(o[r].x * wr - o[r].y * wi,
                                 o[r].x * wi + o[r].y * wr);
        float nr = wr * cb - wi * sb, ni = wr * sb + wi * cb;
        wr = nr; wi = ni;
    }
    __syncthreads();
}

// 8K radix-4 stage at Q=4 (2048 butterflies = 2/thread), twiddle w^r outputs
template <int SGN>
__device__ __forceinline__ void stage8k_dif4(float2* bz, int t) {
    const float sg = (float)SGN;
    #pragma unroll 1
    for (int c = 0; c < 2; ++c) {
        const int j = t + (c << 10);
        const int g = j >> 2;
        const int p = j & 3;
        const int i0 = PD((g << 4) + p);      // PD(e0+4k) = PD(e0)+4k exactly
        float2 z0 = bz[i0], z1 = bz[i0 + 4], z2 = bz[i0 + 8], z3 = bz[i0 + 12];
        float t0r = z0.x + z2.x, t0i = z0.y + z2.y;
        float t1r = z0.x - z2.x, t1i = z0.y - z2.y;
        float t2r = z1.x + z3.x, t2i = z1.y + z3.y;
        float t3r = z1.x - z3.x, t3i = z1.y - z3.y;
        float b0r = t0r + t2r, b0i = t0i + t2i;
        float b2r = t0r - t2r, b2i = t0i - t2i;
        float b1r = t1r - sg * t3i, b1i = t1i + sg * t3r;
        float b3r = t1r + sg * t3i, b3i = t1i - sg * t3r;
        const float a = sg * (float)p * (1.0f / 16.0f);
        const float cb = __builtin_amdgcn_cosf(a);
        const float sb = __builtin_amdgcn_sinf(a);
        const float w2r = cb * cb - sb * sb, w2i = 2.0f * cb * sb;
        const float w3r = cb * w2r - sb * w2i, w3i = cb * w2i + sb * w2r;
        bz[i0]      = make_float2(b0r, b0i);
        bz[i0 + 4]  = make_float2(b1r * cb - b1i * sb,   b1r * sb + b1i * cb);
        bz[i0 + 8]  = make_float2(b2r * w2r - b2i * w2i, b2r * w2i + b2i * w2r);
        bz[i0 + 12] = make_float2(b3r * w3r - b3i * w3i, b3r * w3i + b3i * w3r);
    }
    __syncthreads();
}

// 8K twiddle-free radix-4 on contiguous quads (Q=1, 2/thread)
template <int SGN>
__device__ __forceinline__ void stage8k_nt4(float2* bz, int t) {
    const float sg = (float)SGN;
    #pragma unroll 1
    for (int c = 0; c < 2; ++c) {
        const int j = t + (c << 10);
        const int i0 = 4 * j + (j >> 2) + (j >> 6);
        float2 z0 = bz[i0], z1 = bz[i0 + 1], z2 = bz[i0 + 2], z3 = bz[i0 + 3];
        float t0r = z0.x + z2.x, t0i = z0.y + z2.y;
        float t1r = z0.x - z2.x, t1i = z0.y - z2.y;
        float t2r = z1.x + z3.x, t2i = z1.y + z3.y;
        float t3r = z1.x - z3.x, t3i = z1.y - z3.y;
        bz[i0]     = make_float2(t0r + t2r, t0i + t2i);
        bz[i0 + 2] = make_float2(t0r - t2r, t0i - t2i);
        bz[i0 + 1] = make_float2(t1r - sg * t3i, t1i + sg * t3r);
        bz[i0 + 3] = make_float2(t1r + sg * t3i, t1i - sg * t3r);
    }
    __syncthreads();
}

// ---------------------------------------------------------------------------
// Mega-kernel: one block per row: Pearson, MI, ONE forward 16K FFT (shared by
// power spectrum AND phase correlation via the Hann spectral identity), then
// a HALF-SIZE (8K) complex IFFT for the real correlation surface:
//   B[m] = (C[m]+conj(C[M-m])) + i*W^m*(C[m]-conj(C[M-m])), M=8192,
//   z[n] = IFFT_M(B) -> z.x = c[2n], z.y = c[2n+1]  (scales dropped; argmax
//   is scale-invariant).
// ---------------------------------------------------------------------------
__global__ __launch_bounds__(1024, 4) void k_main(const float* __restrict__ pred,
                                                  const float* __restrict__ targ,
                                                  const int* __restrict__ ip,
                                                  float* __restrict__ wpear,
                                                  float* __restrict__ wcos,
                                                  double* __restrict__ wnum,
                                                  double* __restrict__ wden,
                                                  float* __restrict__ wnmi) {
    __shared__ float2 sz[NPD];
    __shared__ double dpart[16 * 5];
    __shared__ float fpart[16 * 4];
    __shared__ int   subhist[400];
    __shared__ float hxm[10], hym[10];
    __shared__ float mterm[128];
    __shared__ float sbounds[4];
    __shared__ float svalw[16];
    __shared__ int   sidxw[16];

    const int row = blockIdx.x;
    const int t = threadIdx.x;
    const int w = t >> 6;
    const int lane = t & 63;
    float2* bz = &sz[BBASE];

    const float* xg = pred + (size_t)ip[0] * (size_t)BB * SS + (size_t)row * SS;
    const float* yg = targ + (size_t)row * SS;

    // ---- Load (float4) + Pearson sums (fp64) + min/max, streaming into LDS
    {
        const float4* xg4 = reinterpret_cast<const float4*>(xg);
        const float4* yg4 = reinterpret_cast<const float4*>(yg);
        double sx = 0, sy = 0, sxy = 0, sxx = 0, syy = 0;
        float xmn = 3.4e38f, xmx = -3.4e38f, ymn = 3.4e38f, ymx = -3.4e38f;
        #pragma unroll
        for (int m2 = 0; m2 < 4; ++m2) {
            int idx = t + (m2 << 10);          // float4 index
            float4 a = xg4[idx];
            float4 b = yg4[idx];
            int n0 = idx << 2;
            sz[PD(n0 + 0)] = make_float2(a.x, b.x);
            sz[PD(n0 + 1)] = make_float2(a.y, b.y);
            sz[PD(n0 + 2)] = make_float2(a.z, b.z);
            sz[PD(n0 + 3)] = make_float2(a.w, b.w);
            float av[4] = {a.x, a.y, a.z, a.w};
            float bv[4] = {b.x, b.y, b.z, b.w};
            #pragma unroll
            for (int c = 0; c < 4; ++c) {
                float aa = av[c], bb = bv[c];
                sx += (double)aa; sy += (double)bb;
                sxy += (double)aa * (double)bb;
                sxx += (double)aa * (double)aa;
                syy += (double)bb * (double)bb;
                xmn = fminf(xmn, aa); xmx = fmaxf(xmx, aa);
                ymn = fminf(ymn, bb); ymx = fmaxf(ymx, bb);
            }
        }
        #pragma unroll
        for (int o = 32; o > 0; o >>= 1) {
            sx += __shfl_down(sx, o, 64);  sy += __shfl_down(sy, o, 64);
            sxy += __shfl_down(sxy, o, 64);
            sxx += __shfl_down(sxx, o, 64); syy += __shfl_down(syy, o, 64);
            xmn = fminf(xmn, __shfl_down(xmn, o, 64));
            xmx = fmaxf(xmx, __shfl_down(xmx, o, 64));
            ymn = fminf(ymn, __shfl_down(ymn, o, 64));
            ymx = fmaxf(ymx, __shfl_down(ymx, o, 64));
        }
        if (lane == 0) {
            dpart[w*5+0] = sx; dpart[w*5+1] = sy; dpart[w*5+2] = sxy;
            dpart[w*5+3] = sxx; dpart[w*5+4] = syy;
            fpart[w*4+0] = xmn; fpart[w*4+1] = xmx; fpart[w*4+2] = ymn; fpart[w*4+3] = ymx;
        }
    }
    if (t < 400) subhist[t] = 0;
    __syncthreads();
    if (t == 0) {
        double v0=0,v1=0,v2=0,v3=0,v4=0;
        float b0=fpart[0], b1=fpart[1], b2=fpart[2], b3=fpart[3];
        for (int q = 0; q < 16; ++q) {
            v0 += dpart[q*5]; v1 += dpart[q*5+1]; v2 += dpart[q*5+2];
            v3 += dpart[q*5+3]; v4 += dpart[q*5+4];
            b0 = fminf(b0, fpart[q*4]);   b1 = fmaxf(b1, fpart[q*4+1]);
            b2 = fminf(b2, fpart[q*4+2]); b3 = fmaxf(b3, fpart[q*4+3]);
        }
        double N = (double)SS;
        double num = N * v2 - v0 * v1;
        double den = sqrt((N * v3 - v0 * v0) * (N * v4 - v1 * v1));
        wpear[row] = (float)(1.0 - num / den);
        sbounds[0] = b0; sbounds[1] = b1; sbounds[2] = b2; sbounds[3] = b3;
    }
    __syncthreads();

    // ---- MI histogram (x,y re-read from LDS; 4 sub-hists cut atomic contention)
    {
        const float x0 = sbounds[0], bwx = (sbounds[1] - x0) / 10.0f;
        const float y0 = sbounds[2], bwy = (sbounds[3] - y0) / 10.0f;
        int* hsub = subhist + ((t >> 6) & 3) * 100;
        #pragma unroll 2
        for (int m = 0; m < 16; ++m) {
            float2 v = sz[PD(t + (m << 10))];
            int ix = (int)((v.x - x0) / bwx); ix = min(max(ix, 0), 9);
            int iy = (int)((v.y - y0) / bwy); iy = min(max(iy, 0), 9);
            atomicAdd(&hsub[ix * 10 + iy], 1);
        }
    }
    __syncthreads();
    if (t < 100) subhist[t] = subhist[t] + subhist[100+t] + subhist[200+t] + subhist[300+t];
    __syncthreads();
    if (t < 10) {
        int s1 = 0, s2 = 0;
        for (int j = 0; j < 10; ++j) { s1 += subhist[t*10+j]; s2 += subhist[j*10+t]; }
        hxm[t] = (float)s1; hym[t] = (float)s2;
    }
    __syncthreads();
    {
        float term = 0.0f;
        if (t < 100) {
            const float denom = 8388608.0f, eps = 1e-8f;
            float pxy = (float)subhist[t] / denom;
            float px = hxm[t / 10] / denom, py = hym[t % 10] / denom;
            term = pxy * logf((pxy + eps) / (px * py + eps));
        }
        if (t < 128) mterm[t] = (t < 100) ? term : 0.0f;
    }
    __syncthreads();
    if (t == 0) {
        const float denom = 8388608.0f, eps = 1e-8f;
        float mi = 0.0f;
        for (int q = 0; q < 100; ++q) mi += mterm[q];
        float hxe = 0.0f, hye = 0.0f;
        for (int q = 0; q < 10; ++q) {
            float px = hxm[q] / denom, py = hym[q] / denom;
            hxe -= px * logf(px + eps);
            hye -= py * logf(py + eps);
        }
        wnmi[row] = mi / (0.5f * (hxe + hye));
    }
    __syncthreads();

    // ---- FFT1 (shared forward DIF, radix 8x4 then 4): natural -> s-order
    stage_dif8<-1, 11>(sz, t);   // Q=2048
    stage_dif8<-1,  8>(sz, t);   // Q=256
    stage_dif8<-1,  5>(sz, t);   // Q=32
    stage_dif8<-1,  2>(sz, t);   // Q=4
    stage_nt4<-1>(sz, t);        // Q=1, twiddle-free

    // ---- Fused unpack: power sums (unwindowed) + phase-correlation C from
    //      the Hann-convolved spectrum (Zw[k] = 0.5Z[k]-0.25(Z[k-1]+Z[k+1]),
    //      exact for the periodic window). Reads before barrier; C written
    //      to NATURAL slots [0..8192] after (spectrum is dead by then).
    {
        double anum = 0.0, aden = 0.0;
        float crv[8], civ[8];
        #pragma unroll 1
        for (int m = 0; m < 8; ++m) {
            int k = t + (m << 10);
            int km = (SS - k) & (SS - 1);
            float2 za = sz[sp(k)];
            float2 zb = sz[sp(km)];
            float ar  = za.x, ai  = za.y;
            float cr0 = zb.x, ci0 = zb.y;
            float xr = 0.5f * (ar + cr0), xi = 0.5f * (ai - ci0);
            float yr = 0.5f * (ai + ci0), yi = 0.5f * (cr0 - ar);
            float xp = xr * xr + xi * xi;
            float tp = yr * yr + yi * yi;
            anum += (double)fabsf(xp - tp);
            aden += (double)tp;
            float2 zap = sz[sp((k + 1) & (SS - 1))];
            float2 zam = sz[sp((k - 1) & (SS - 1))];
            float2 zbp = sz[sp((km + 1) & (SS - 1))];
            float2 zbm = sz[sp((km - 1) & (SS - 1))];
            float zwr = 0.5f * ar  - 0.25f * (zap.x + zam.x);
            float zwi = 0.5f * ai  - 0.25f * (zap.y + zam.y);
            float vwr = 0.5f * cr0 - 0.25f * (zbp.x + zbm.x);
            float vwi = 0.5f * ci0 - 0.25f * (zbp.y + zbm.y);
            float xwr = 0.5f * (zwr + vwr), xwi = 0.5f * (zwi - vwi);
            float ywr = 0.5f * (zwi + vwi), ywi = 0.5f * (vwr - zwr);
            float cr = xwr * ywr + xwi * ywi;
            float ci = xwi * ywr - xwr * ywi;
            float mag = sqrtf(cr * cr + ci * ci);
            crv[m] = cr / mag; civ[m] = ci / mag;
        }
        float c8 = 0.0f;
        if (t == 0) {   // k = 8192 (self-conjugate)
            float2 z0 = sz[sp(8192)];
            float2 zp = sz[sp(8193)];
            float2 zm = sz[sp(8191)];
            float ar = z0.x, ai = z0.y;
            anum += (double)fabsf(ar * ar - ai * ai);
            aden += (double)(ai * ai);
            float zwr = 0.5f * ar - 0.25f * (zp.x + zm.x);
            float zwi = 0.5f * ai - 0.25f * (zp.y + zm.y);
            float pr = zwr * zwi;          // Xw real, Yw real at Nyquist
            c8 = pr / fabsf(pr);
        }
        #pragma unroll
        for (int o = 32; o > 0; o >>= 1) {
            anum += __shfl_down(anum, o, 64);
            aden += __shfl_down(aden, o, 64);
        }
        if (lane == 0) { dpart[w*2] = anum; dpart[w*2+1] = aden; }
        __syncthreads();   // all spectrum reads done; safe to overwrite
        #pragma unroll
        for (int m = 0; m < 8; ++m) {
            int k = t + (m << 10);
            sz[k] = make_float2(crv[m], civ[m]);   // C natural, k in [0,8192)
        }
        if (t == 0) {
            sz[8192] = make_float2(c8, 0.0f);
            double a = 0, b = 0;
            for (int q2_ = 0; q2_ < 16; ++q2_) { a += dpart[q2_*2]; b += dpart[q2_*2+1]; }
            wnum[row] = a; wden[row] = b;
        }
    }
    __syncthreads();

    // ---- Build B[m] for the 8K real-output IFFT; W^m via chained 1/16-turn.
    {
        float a0 = (float)t * (1.0f / 16384.0f);
        float wr = __builtin_amdgcn_cosf(a0);
        float wi = __builtin_amdgcn_sinf(a0);
        const float cs = 0.92387953251128674f;  // cos(2pi/16)
        const float sn = 0.38268343236508977f;  // sin(2pi/16)
        const int pdt = PD(t);
        #pragma unroll 1
        for (int c = 0; c < 8; ++c) {
            int m = t + (c << 10);
            float2 cm = sz[m];
            float2 cn = sz[8192 - m];            // C[M-m]; conj taken inline
            float Ax = cm.x + cn.x, Ay = cm.y - cn.y;   // C[m]+conj(C[M-m])
            float Dx = cm.x - cn.x, Dy = cm.y + cn.y;   // C[m]-conj(C[M-m])
            float WDx = Dx * wr - Dy * wi;
            float WDy = Dx * wi + Dy * wr;
            bz[pdt + c * 1092] = make_float2(Ax - WDy, Ay + WDx);  // PD(m)=PD(t)+1092c
            float nr = wr * cs - wi * sn, ni = wr * sn + wi * cs;
            wr = nr; wi = ni;
        }
    }
    __syncthreads();

    // ---- 8K inverse chain (sign +1, unscaled): natural -> digit-rev slots
    stage8k_dif8<1, 10>(bz, t);   // Q=1024
    stage8k_dif8<1,  7>(bz, t);   // Q=128
    stage8k_dif8<1,  4>(bz, t);   // Q=16
    stage8k_dif4<1>(bz, t);       // Q=4
    stage8k_nt4<1>(bz, t);        // Q=1

    // ---- argmax: slot s = t + c*1024 holds time index n = K(t)+c;
    //      z.x = c[2n] (lag 2n), z.y = c[2n+1]. Tie-break: smallest lag.
    {
        const int K = (((t >> 7) & 7) << 3) + (((t >> 4) & 7) << 6)
                    + (((t >> 2) & 3) << 9) + ((t & 3) << 11);
        const int pdt = PD(t);
        float bv = -3.4e38f; int bi = 0;
        #pragma unroll
        for (int c = 0; c < 8; ++c) {
            float2 z = bz[pdt + c * 1092];
            int n2 = (K + c) << 1;
            if (z.x > bv) { bv = z.x; bi = n2; }
            if (z.y > bv) { bv = z.y; bi = n2 + 1; }
        }
        #pragma unroll
        for (int o = 32; o > 0; o >>= 1) {
            float v2 = __shfl_down(bv, o, 64);
            int i2 = __shfl_down(bi, o, 64);
            if (v2 > bv || (v2 == bv && i2 < bi)) { bv = v2; bi = i2; }
        }
        if (lane == 0) { svalw[w] = bv; sidxw[w] = bi; }
    }
    __syncthreads();
    if (t == 0) {
        float bv = svalw[0]; int bi = sidxw[0];
        for (int q = 1; q < 16; ++q) {
            if (svalw[q] > bv || (svalw[q] == bv && sidxw[q] < bi)) { bv = svalw[q]; bi = sidxw[q]; }
        }
        wcos[row] = cosf(TPIF * (float)bi / 16384.0f);
    }
}

// ---------------------------------------------------------------------------
// Final combine (reads epoch on-device; graph-safe). Wave-shuffle reductions.
// ---------------------------------------------------------------------------
__global__ __launch_bounds__(512) void k_combine(const float* __restrict__ wpear,
                                                 const float* __restrict__ wcos,
                                                 const double* __restrict__ wnum,
                                                 const double* __restrict__ wden,
                                                 const float* __restrict__ wnmi,
                                                 const int* __restrict__ ep,
                                                 float* __restrict__ out) {
    __shared__ double dp[8 * 5];
    const int tid = threadIdx.x;
    const int w = tid >> 6, lane = tid & 63;
    double v0 = (double)wpear[tid], v1 = (double)wcos[tid];
    double v2 = wnum[tid], v3 = wden[tid], v4 = (double)wnmi[tid];
    #pragma unroll
    for (int o = 32; o > 0; o >>= 1) {
        v0 += __shfl_down(v0, o, 64); v1 += __shfl_down(v1, o, 64);
        v2 += __shfl_down(v2, o, 64); v3 += __shfl_down(v3, o, 64);
        v4 += __shfl_down(v4, o, 64);
    }
    if (lane == 0) {
        dp[w*5+0] = v0; dp[w*5+1] = v1; dp[w*5+2] = v2; dp[w*5+3] = v3; dp[w*5+4] = v4;
    }
    __syncthreads();
    if (tid == 0) {
        double s0=0,s1=0,s2=0,s3=0,s4=0;
        for (int q = 0; q < 8; ++q) {
            s0 += dp[q*5]; s1 += dp[q*5+1]; s2 += dp[q*5+2]; s3 += dp[q*5+3]; s4 += dp[q*5+4];
        }
        int epoch = ep[0];
        double loss = s0 / 512.0;
        if (epoch >= 400) {
            loss += 1.0 - s1 / 512.0;
            loss += s2 / s3;
        }
        if (epoch >= 700) {
            loss += 1.0 - s4 / 512.0;
        }
        out[0] = (float)loss;
    }
}

// ---------------------------------------------------------------------------
extern "C" void kernel_launch(void* const* d_in, const int* in_sizes, int n_in,
                              void* d_out, int out_size, void* d_ws, size_t ws_size,
                              hipStream_t stream) {
    const float* pred = (const float*)d_in[0];   // [2, 512, 16384] f32
    const float* targ = (const float*)d_in[1];   // [512, 16384] f32
    const int* ip = (const int*)d_in[2];         // scalar i
    const int* ep = (const int*)d_in[3];         // scalar epoch
    float* out = (float*)d_out;

    double* wnum = (double*)d_ws;                // [512]
    double* wden = wnum + BB;                    // [512]
    float* wpear = (float*)(wden + BB);          // [512]
    float* wcos = wpear + BB;                    // [512]
    float* wnmi = wcos + BB;                     // [512]

    k_main<<<dim3(BB), dim3(1024), 0, stream>>>(pred, targ, ip, wpear, wcos, wnum, wden, wnmi);
    k_combine<<<dim3(1), dim3(512), 0, stream>>>(wpear, wcos, wnum, wden, wnmi, ep, out);
}

// Round 10
// 180.232 us; speedup vs baseline: 1.4205x; 1.0558x over previous
//
#include <hip/hip_runtime.h>
#include <math.h>

#define BB 512
#define SS 16384
#define TPIF 6.28318530717958647692f

// float2 (b64) element pad. Measured "conflicts" are the structural b64 floor
// (4 lanes/bank-pair); layout already optimal -- do not re-tune.
#define PD(i) ((i) + ((i) >> 4) + ((i) >> 8))
#define NPD 17472   // PD(16383)=17469 < 17472; 139.8 KB of LDS
#define BBASE 8200  // 8K-IFFT region base; C natural occupies slots [0..8192]

// mixed-radix [8,8,8,8,4] storage map for the 16K forward DIF: frequency k
// lives at element s(k). R6 lesson: always wrap with PD().
__device__ __forceinline__ int sp(int k) {
    int s = ((k & 7) << 11) + (((k >> 3) & 7) << 8) + (((k >> 6) & 7) << 5)
          + (((k >> 9) & 7) << 2) + ((k >> 12) & 3);
    return PD(s);
}

// ---------------------------------------------------------------------------
// 64-VGPR design rule (R0-R9 evidence): allocator pins this kernel at 64
// VGPRs; keep <=~45 live everywhere. R10: phase fusion -- MI binning rides
// forward stage 1 (which reads every element once anyway); B-build feeds the
// first inverse butterfly in registers; argmax rides the last butterfly.
// ---------------------------------------------------------------------------

// 16K radix-8 DIF stage (2 butterflies/thread), twiddle w^r on outputs.
// DOMI=true additionally bins raw element values into the MI histogram.
template <int SGN, int LOG2Q, bool DOMI = false>
__device__ __forceinline__ void stage_dif8(float2* sz, int t,
                                           float x0 = 0.f, float sbx = 0.f,
                                           float y0 = 0.f, float sby = 0.f,
                                           int* hsub = nullptr) {
    constexpr int Q = 1 << LOG2Q;
    constexpr int DQ = Q + (Q >> 4) + (Q >> 8);
    const float sg = (float)SGN;
    const float r2 = 0.70710678118654752f;
    #pragma unroll 1
    for (int c = 0; c < 2; ++c) {
        const int j = t + (c << 10);
        const int g = j >> LOG2Q;
        const int p = j & (Q - 1);
        const int i0 = PD((g << (LOG2Q + 3)) + p);
        int idx[8];
        #pragma unroll
        for (int k = 0; k < 8; ++k)
            idx[k] = (LOG2Q >= 4) ? (i0 + k * DQ) : (i0 + 4 * k + (k >> 2));  // Q=4 carry fix
        float2 z[8];
        #pragma unroll
        for (int k = 0; k < 8; ++k) z[k] = sz[idx[k]];
        if constexpr (DOMI) {   // bin raw values (first touch of each element)
            #pragma unroll
            for (int k = 0; k < 8; ++k) {
                int ix = (int)((z[k].x - x0) * sbx); ix = min(max(ix, 0), 9);
                int iy = (int)((z[k].y - y0) * sby); iy = min(max(iy, 0), 9);
                atomicAdd(&hsub[ix * 10 + iy], 1);
            }
        }
        float2 a0, a1, a2, a3, b0, b1, b2, b3;
        a0 = make_float2(z[0].x + z[4].x, z[0].y + z[4].y);
        b0 = make_float2(z[0].x - z[4].x, z[0].y - z[4].y);
        a1 = make_float2(z[1].x + z[5].x, z[1].y + z[5].y);
        b1 = make_float2(z[1].x - z[5].x, z[1].y - z[5].y);
        a2 = make_float2(z[2].x + z[6].x, z[2].y + z[6].y);
        b2 = make_float2(z[2].x - z[6].x, z[2].y - z[6].y);
        a3 = make_float2(z[3].x + z[7].x, z[3].y + z[7].y);
        b3 = make_float2(z[3].x - z[7].x, z[3].y - z[7].y);
        { float x = b1.x, y = b1.y; b1 = make_float2(r2 * (x - sg * y), r2 * (y + sg * x)); }
        { float x = b2.x, y = b2.y; b2 = make_float2(-sg * y, sg * x); }
        { float x = b3.x, y = b3.y; b3 = make_float2(-r2 * (x + sg * y), r2 * (sg * x - y)); }
        float2 o[8];
        {
            float t0r = a0.x + a2.x, t0i = a0.y + a2.y;
            float t1r = a0.x - a2.x, t1i = a0.y - a2.y;
            float t2r = a1.x + a3.x, t2i = a1.y + a3.y;
            float t3r = a1.x - a3.x, t3i = a1.y - a3.y;
            o[0] = make_float2(t0r + t2r, t0i + t2i);
            o[4] = make_float2(t0r - t2r, t0i - t2i);
            o[2] = make_float2(t1r - sg * t3i, t1i + sg * t3r);
            o[6] = make_float2(t1r + sg * t3i, t1i - sg * t3r);
        }
        {
            float t0r = b0.x + b2.x, t0i = b0.y + b2.y;
            float t1r = b0.x - b2.x, t1i = b0.y - b2.y;
            float t2r = b1.x + b3.x, t2i = b1.y + b3.y;
            float t3r = b1.x - b3.x, t3i = b1.y - b3.y;
            o[1] = make_float2(t0r + t2r, t0i + t2i);
            o[5] = make_float2(t0r - t2r, t0i - t2i);
            o[3] = make_float2(t1r - sg * t3i, t1i + sg * t3r);
            o[7] = make_float2(t1r + sg * t3i, t1i - sg * t3r);
        }
        const float arev = sg * (float)p * (1.0f / (8.0f * (float)Q));  // revolutions
        const float cb = __builtin_amdgcn_cosf(arev);
        const float sb = __builtin_amdgcn_sinf(arev);
        sz[idx[0]] = o[0];
        float wr = cb, wi = sb;
        #pragma unroll
        for (int r = 1; r < 8; ++r) {
            sz[idx[r]] = make_float2(o[r].x * wr - o[r].y * wi,
                                     o[r].x * wi + o[r].y * wr);
            float nr = wr * cb - wi * sb, ni = wr * sb + wi * cb;
            wr = nr; wi = ni;
        }
    }
    __syncthreads();
}

// 16K twiddle-free radix-4 stage on contiguous quads (Q=1, 4/thread)
template <int SGN>
__device__ __forceinline__ void stage_nt4(float2* sz, int t) {
    const float sg = (float)SGN;
    #pragma unroll 1
    for (int c = 0; c < 4; ++c) {
        const int j = t + (c << 10);
        const int i0 = 4 * j + (j >> 2) + (j >> 6);   // PD(4j); PD(4j+k)=i0+k
        float2 z0 = sz[i0], z1 = sz[i0 + 1], z2 = sz[i0 + 2], z3 = sz[i0 + 3];
        float t0r = z0.x + z2.x, t0i = z0.y + z2.y;
        float t1r = z0.x - z2.x, t1i = z0.y - z2.y;
        float t2r = z1.x + z3.x, t2i = z1.y + z3.y;
        float t3r = z1.x - z3.x, t3i = z1.y - z3.y;
        sz[i0]     = make_float2(t0r + t2r, t0i + t2i);
        sz[i0 + 2] = make_float2(t0r - t2r, t0i - t2i);
        sz[i0 + 1] = make_float2(t1r - sg * t3i, t1i + sg * t3r);
        sz[i0 + 3] = make_float2(t1r + sg * t3i, t1i - sg * t3r);
    }
    __syncthreads();
}

// ---------------------------------------------------------------------------
// 8K (half-size, real-output) inverse chain, region base bz = sz+BBASE.
// Chain: [fused B+r8 Q=1024], r8 Q=128, r8 Q=16, r4 Q=4, [fused r4 Q=1+argmax]
// Output map: time-lag n at slot (n&7)*1024 + ((n>>3)&7)*128 + ((n>>6)&7)*16
//             + ((n>>9)&3)*4 + (n>>11).
// PD increments: Q=1024 -> 1092 exact; Q=16 -> 17 exact; Q=128 -> 136k+(k>>1).
// ---------------------------------------------------------------------------
template <int SGN, int LOG2Q>
__device__ __forceinline__ void stage8k_dif8(float2* bz, int t) {
    constexpr int Q = 1 << LOG2Q;
    constexpr int DQ = Q + (Q >> 4) + (Q >> 8);
    constexpr int CORR = (LOG2Q == 7) ? 1 : 0;
    const float sg = (float)SGN;
    const float r2 = 0.70710678118654752f;
    const int g = t >> LOG2Q;                 // 1024 butterflies = 1/thread
    const int p = t & (Q - 1);
    const int i0 = PD((g << (LOG2Q + 3)) + p);
    int idx[8];
    #pragma unroll
    for (int k = 0; k < 8; ++k) idx[k] = i0 + k * DQ + CORR * (k >> 1);
    float2 z[8];
    #pragma unroll
    for (int k = 0; k < 8; ++k) z[k] = bz[idx[k]];
    float2 a0, a1, a2, a3, b0, b1, b2, b3;
    a0 = make_float2(z[0].x + z[4].x, z[0].y + z[4].y);
    b0 = make_float2(z[0].x - z[4].x, z[0].y - z[4].y);
    a1 = make_float2(z[1].x + z[5].x, z[1].y + z[5].y);
    b1 = make_float2(z[1].x - z[5].x, z[1].y - z[5].y);
    a2 = make_float2(z[2].x + z[6].x, z[2].y + z[6].y);
    b2 = make_float2(z[2].x - z[6].x, z[2].y - z[6].y);
    a3 = make_float2(z[3].x + z[7].x, z[3].y + z[7].y);
    b3 = make_float2(z[3].x - z[7].x, z[3].y - z[7].y);
    { float x = b1.x, y = b1.y; b1 = make_float2(r2 * (x - sg * y), r2 * (y + sg * x)); }
    { float x = b2.x, y = b2.y; b2 = make_float2(-sg * y, sg * x); }
    { float x = b3.x, y = b3.y; b3 = make_float2(-r2 * (x + sg * y), r2 * (sg * x - y)); }
    float2 o[8];
    {
        float t0r = a0.x + a2.x, t0i = a0.y + a2.y;
        float t1r = a0.x - a2.x, t1i = a0.y - a2.y;
        float t2r = a1.x + a3.x, t2i = a1.y + a3.y;
        float t3r = a1.x - a3.x, t3i = a1.y - a3.y;
        o[0] = make_float2(t0r + t2r, t0i + t2i);
        o[4] = make_float2(t0r - t2r, t0i - t2i);
        o[2] = make_float2(t1r - sg * t3i, t1i + sg * t3r);
        o[6] = make_float2(t1r + sg * t3i, t1i - sg * t3r);
    }
    {
        float t0r = b0.x + b2.x, t0i = b0.y + b2.y;
        float t1r = b0.x - b2.x, t1i = b0.y - b2.y;
        float t2r = b1.x + b3.x, t2i = b1.y + b3.y;
        float t3r = b1.x - b3.x, t3i = b1.y - b3.y;
        o[1] = make_float2(t0r + t2r, t0i + t2i);
        o[5] = make_float2(t0r - t2r, t0i - t2i);
        o[3] = make_float2(t1r - sg * t3i, t1i + sg * t3r);
        o[7] = make_float2(t1r + sg * t3i, t1i - sg * t3r);
    }
    const float arev = sg * (float)p * (1.0f / (8.0f * (float)Q));  // revolutions
    const float cb = __builtin_amdgcn_cosf(arev);
    const float sb = __builtin_amdgcn_sinf(arev);
    bz[idx[0]] = o[0];
    float wr = cb, wi = sb;
    #pragma unroll
    for (int r = 1; r < 8; ++r) {
        bz[idx[r]] = make_float2(o[r].x * wr - o[r].y * wi,
                                 o[r].x * wi + o[r].y * wr);
        float nr = wr * cb - wi * sb, ni = wr * sb + wi * cb;
        wr = nr; wi = ni;
    }
    __syncthreads();
}

// FUSED: build B[m] in registers from C (natural slots in sz) and run the
// first inverse stage (Q=1024, g=0, p=t) directly on it.
// B[m] = (C[m]+conj(C[M-m])) + i*W^m*(C[m]-conj(C[M-m])), W=e^{+2pi i/16384};
// thread t needs exactly B[t + 1024c], c=0..7 -- the values it builds.
__device__ __forceinline__ void inv_first(float2* sz, float2* bz, int t) {
    const float r2 = 0.70710678118654752f;
    float2 z[8];
    {
        float a0w = (float)t * (1.0f / 16384.0f);
        float wr = __builtin_amdgcn_cosf(a0w);
        float wi = __builtin_amdgcn_sinf(a0w);
        const float cs = 0.92387953251128674f;  // cos(2pi/16)
        const float sn = 0.38268343236508977f;  // sin(2pi/16)
        #pragma unroll
        for (int c = 0; c < 8; ++c) {
            int m = t + (c << 10);
            float2 cm = sz[m];
            float2 cn = sz[8192 - m];
            float Ax = cm.x + cn.x, Ay = cm.y - cn.y;
            float Dx = cm.x - cn.x, Dy = cm.y + cn.y;
            float WDx = Dx * wr - Dy * wi;
            float WDy = Dx * wi + Dy * wr;
            z[c] = make_float2(Ax - WDy, Ay + WDx);
            float nr = wr * cs - wi * sn, ni = wr * sn + wi * cs;
            wr = nr; wi = ni;
        }
    }
    // Q=1024 DIF butterfly, SGN=+1, i0=PD(t), stride 1092
    const float sg = 1.0f;
    const int i0 = PD(t);
    float2 a0, a1, a2, a3, b0, b1, b2, b3;
    a0 = make_float2(z[0].x + z[4].x, z[0].y + z[4].y);
    b0 = make_float2(z[0].x - z[4].x, z[0].y - z[4].y);
    a1 = make_float2(z[1].x + z[5].x, z[1].y + z[5].y);
    b1 = make_float2(z[1].x - z[5].x, z[1].y - z[5].y);
    a2 = make_float2(z[2].x + z[6].x, z[2].y + z[6].y);
    b2 = make_float2(z[2].x - z[6].x, z[2].y - z[6].y);
    a3 = make_float2(z[3].x + z[7].x, z[3].y + z[7].y);
    b3 = make_float2(z[3].x - z[7].x, z[3].y - z[7].y);
    { float x = b1.x, y = b1.y; b1 = make_float2(r2 * (x - sg * y), r2 * (y + sg * x)); }
    { float x = b2.x, y = b2.y; b2 = make_float2(-sg * y, sg * x); }
    { float x = b3.x, y = b3.y; b3 = make_float2(-r2 * (x + sg * y), r2 * (sg * x - y)); }
    float2 o[8];
    {
        float t0r = a0.x + a2.x, t0i = a0.y + a2.y;
        float t1r = a0.x - a2.x, t1i = a0.y - a2.y;
        float t2r = a1.x + a3.x, t2i = a1.y + a3.y;
        float t3r = a1.x - a3.x, t3i = a1.y - a3.y;
        o[0] = make_float2(t0r + t2r, t0i + t2i);
        o[4] = make_float2(t0r - t2r, t0i - t2i);
        o[2] = make_float2(t1r - sg * t3i, t1i + sg * t3r);
        o[6] = make_float2(t1r + sg * t3i, t1i - sg * t3r);
    }
    {
        float t0r = b0.x + b2.x, t0i = b0.y + b2.y;
        float t1r = b0.x - b2.x, t1i = b0.y - b2.y;
        float t2r = b1.x + b3.x, t2i = b1.y + b3.y;
        float t3r = b1.x - b3.x, t3i = b1.y - b3.y;
        o[1] = make_float2(t0r + t2r, t0i + t2i);
        o[5] = make_float2(t0r - t2r, t0i - t2i);
        o[3] = make_float2(t1r - sg * t3i, t1i + sg * t3r);
        o[7] = make_float2(t1r + sg * t3i, t1i - sg * t3r);
    }
    const float arev = (float)t * (1.0f / 8192.0f);  // +p/(8Q) revolutions
    const float cb = __builtin_amdgcn_cosf(arev);
    const float sb = __builtin_amdgcn_sinf(arev);
    bz[i0] = o[0];
    float wr = cb, wi = sb;
    #pragma unroll
    for (int r = 1; r < 8; ++r) {
        bz[i0 + r * 1092] = make_float2(o[r].x * wr - o[r].y * wi,
                                        o[r].x * wi + o[r].y * wr);
        float nr = wr * cb - wi * sb, ni = wr * sb + wi * cb;
        wr = nr; wi = ni;
    }
    __syncthreads();
}

// 8K radix-4 stage at Q=4 (2048 butterflies = 2/thread), twiddle w^r outputs
template <int SGN>
__device__ __forceinline__ void stage8k_dif4(float2* bz, int t) {
    const float sg = (float)SGN;
    #pragma unroll 1
    for (int c = 0; c < 2; ++c) {
        const int j = t + (c << 10);
        const int g = j >> 2;
        const int p = j & 3;
        const int i0 = PD((g << 4) + p);      // PD(e0+4k) = PD(e0)+4k exactly
        float2 z0 = bz[i0], z1 = bz[i0 + 4], z2 = bz[i0 + 8], z3 = bz[i0 + 12];
        float t0r = z0.x + z2.x, t0i = z0.y + z2.y;
        float t1r = z0.x - z2.x, t1i = z0.y - z2.y;
        float t2r = z1.x + z3.x, t2i = z1.y + z3.y;
        float t3r = z1.x - z3.x, t3i = z1.y - z3.y;
        float b0r = t0r + t2r, b0i = t0i + t2i;
        float b2r = t0r - t2r, b2i = t0i - t2i;
        float b1r = t1r - sg * t3i, b1i = t1i + sg * t3r;
        float b3r = t1r + sg * t3i, b3i = t1i - sg * t3r;
        const float a = sg * (float)p * (1.0f / 16.0f);
        const float cb = __builtin_amdgcn_cosf(a);
        const float sb = __builtin_amdgcn_sinf(a);
        const float w2r = cb * cb - sb * sb, w2i = 2.0f * cb * sb;
        const float w3r = cb * w2r - sb * w2i, w3i = cb * w2i + sb * w2r;
        bz[i0]      = make_float2(b0r, b0i);
        bz[i0 + 4]  = make_float2(b1r * cb - b1i * sb,   b1r * sb + b1i * cb);
        bz[i0 + 8]  = make_float2(b2r * w2r - b2i * w2i, b2r * w2i + b2i * w2r);
        bz[i0 + 12] = make_float2(b3r * w3r - b3i * w3i, b3r * w3i + b3i * w3r);
    }
    __syncthreads();
}

// FUSED: last (Q=1, twiddle-free) radix-4 stage + argmax -- outputs are
// consumed in registers, never stored. Slot 4j+k' holds time index
// n = (j>>8) + 8*((j>>5)&7) + 64*((j>>2)&7) + 512*(j&3) + 2048*k';
// z.x = c[2n] (lag 2n), z.y = c[2n+1]. Tie-break: smallest lag.
__device__ __forceinline__ void inv_last_argmax(float2* bz, int t, float* pbv, int* pbi) {
    float bv = -3.4e38f; int bi = 0;
    #pragma unroll 1
    for (int c = 0; c < 2; ++c) {
        const int j = t + (c << 10);
        const int i0 = 4 * j + (j >> 2) + (j >> 6);
        float2 z0 = bz[i0], z1 = bz[i0 + 1], z2 = bz[i0 + 2], z3 = bz[i0 + 3];
        float t0r = z0.x + z2.x, t0i = z0.y + z2.y;
        float t1r = z0.x - z2.x, t1i = z0.y - z2.y;
        float t2r = z1.x + z3.x, t2i = z1.y + z3.y;
        float t3r = z1.x - z3.x, t3i = z1.y - z3.y;
        float re[4], im[4];
        re[0] = t0r + t2r; im[0] = t0i + t2i;   // k'=0
        re[1] = t1r - t3i; im[1] = t1i + t3r;   // k'=1 (sg=+1)
        re[2] = t0r - t2r; im[2] = t0i - t2i;   // k'=2
        re[3] = t1r + t3i; im[3] = t1i - t3r;   // k'=3
        const int nb = (j >> 8) + ((j >> 5) & 7) * 8 + ((j >> 2) & 7) * 64 + (j & 3) * 512;
        #pragma unroll
        for (int k = 0; k < 4; ++k) {
            int n2 = (nb + 2048 * k) << 1;
            if (re[k] > bv || (re[k] == bv && n2 < bi)) { bv = re[k]; bi = n2; }
            if (im[k] > bv || (im[k] == bv && n2 + 1 < bi)) { bv = im[k]; bi = n2 + 1; }
        }
    }
    *pbv = bv; *pbi = bi;
}

// ---------------------------------------------------------------------------
// Mega-kernel: one block per row: Pearson, MI (fused into FFT stage 1), ONE
// forward 16K FFT (shared by power spectrum AND phase correlation via the
// Hann spectral identity), then a HALF-SIZE (8K) real-output inverse FFT
// with fused endpoints.
// ---------------------------------------------------------------------------
__global__ __launch_bounds__(1024, 4) void k_main(const float* __restrict__ pred,
                                                  const float* __restrict__ targ,
                                                  const int* __restrict__ ip,
                                                  float* __restrict__ wpear,
                                                  float* __restrict__ wcos,
                                                  double* __restrict__ wnum,
                                                  double* __restrict__ wden,
                                                  float* __restrict__ wnmi) {
    __shared__ float2 sz[NPD];
    __shared__ double dpart[16 * 5];
    __shared__ float fpart[16 * 4];
    __shared__ int   subhist[1600];          // 16 per-warp sub-histograms
    __shared__ float hxm[10], hym[10];
    __shared__ float mterm[128];
    __shared__ float sbounds[4];             // x0, 10/(xmax-x0), y0, 10/(ymax-y0)
    __shared__ float svalw[16];
    __shared__ int   sidxw[16];

    const int row = blockIdx.x;
    const int t = threadIdx.x;
    const int w = t >> 6;
    const int lane = t & 63;
    float2* bz = &sz[BBASE];

    const float* xg = pred + (size_t)ip[0] * (size_t)BB * SS + (size_t)row * SS;
    const float* yg = targ + (size_t)row * SS;

    // ---- Load (float4) + Pearson sums (fp32 partials) + min/max, streaming
    //      into LDS (sz = x + i y == FFT1 input, natural order).
    {
        const float4* xg4 = reinterpret_cast<const float4*>(xg);
        const float4* yg4 = reinterpret_cast<const float4*>(yg);
        float sx = 0, sy = 0, sxy = 0, sxx = 0, syy = 0;
        float xmn = 3.4e38f, xmx = -3.4e38f, ymn = 3.4e38f, ymx = -3.4e38f;
        #pragma unroll
        for (int m2 = 0; m2 < 4; ++m2) {
            int idx = t + (m2 << 10);          // float4 index
            float4 a = xg4[idx];
            float4 b = yg4[idx];
            int n0 = idx << 2;
            sz[PD(n0 + 0)] = make_float2(a.x, b.x);
            sz[PD(n0 + 1)] = make_float2(a.y, b.y);
            sz[PD(n0 + 2)] = make_float2(a.z, b.z);
            sz[PD(n0 + 3)] = make_float2(a.w, b.w);
            float av[4] = {a.x, a.y, a.z, a.w};
            float bv[4] = {b.x, b.y, b.z, b.w};
            #pragma unroll
            for (int c = 0; c < 4; ++c) {
                float aa = av[c], bb = bv[c];
                sx += aa; sy += bb;
                sxy += aa * bb;
                sxx += aa * aa;
                syy += bb * bb;
                xmn = fminf(xmn, aa); xmx = fmaxf(xmx, aa);
                ymn = fminf(ymn, bb); ymx = fmaxf(ymx, bb);
            }
        }
        #pragma unroll
        for (int o = 32; o > 0; o >>= 1) {
            sx += __shfl_down(sx, o, 64);  sy += __shfl_down(sy, o, 64);
            sxy += __shfl_down(sxy, o, 64);
            sxx += __shfl_down(sxx, o, 64); syy += __shfl_down(syy, o, 64);
            xmn = fminf(xmn, __shfl_down(xmn, o, 64));
            xmx = fmaxf(xmx, __shfl_down(xmx, o, 64));
            ymn = fminf(ymn, __shfl_down(ymn, o, 64));
            ymx = fmaxf(ymx, __shfl_down(ymx, o, 64));
        }
        if (lane == 0) {
            dpart[w*5+0] = (double)sx; dpart[w*5+1] = (double)sy;
            dpart[w*5+2] = (double)sxy;
            dpart[w*5+3] = (double)sxx; dpart[w*5+4] = (double)syy;
            fpart[w*4+0] = xmn; fpart[w*4+1] = xmx; fpart[w*4+2] = ymn; fpart[w*4+3] = ymx;
        }
    }
    subhist[t] = 0;
    if (t < 576) subhist[1024 + t] = 0;
    __syncthreads();
    if (t == 0) {
        double v0=0,v1=0,v2=0,v3=0,v4=0;
        float b0=fpart[0], b1=fpart[1], b2=fpart[2], b3=fpart[3];
        for (int q = 0; q < 16; ++q) {
            v0 += dpart[q*5]; v1 += dpart[q*5+1]; v2 += dpart[q*5+2];
            v3 += dpart[q*5+3]; v4 += dpart[q*5+4];
            b0 = fminf(b0, fpart[q*4]);   b1 = fmaxf(b1, fpart[q*4+1]);
            b2 = fminf(b2, fpart[q*4+2]); b3 = fmaxf(b3, fpart[q*4+3]);
        }
        double N = (double)SS;
        double num = N * v2 - v0 * v1;
        double den = sqrt((N * v3 - v0 * v0) * (N * v4 - v1 * v1));
        wpear[row] = (float)(1.0 - num / den);
        sbounds[0] = b0; sbounds[1] = 10.0f / (b1 - b0);
        sbounds[2] = b2; sbounds[3] = 10.0f / (b3 - b2);
    }
    __syncthreads();

    // ---- FFT1 stage 1 (Q=2048) with FUSED MI binning (reads every element
    //      exactly once, pre-butterfly values are the raw x,y).
    {
        const float x0 = sbounds[0], sbx = sbounds[1];
        const float y0 = sbounds[2], sby = sbounds[3];
        int* hsub = subhist + w * 100;       // one sub-hist per warp
        stage_dif8<-1, 11, true>(sz, t, x0, sbx, y0, sby, hsub);
    }

    // ---- MI finalize (subhist complete after stage-1 barrier)
    if (t < 100) {
        int s = 0;
        #pragma unroll
        for (int q = 0; q < 16; ++q) s += subhist[t + 100 * q];
        subhist[t] = s;
    }
    __syncthreads();
    if (t < 10) {
        int s1 = 0, s2 = 0;
        for (int j = 0; j < 10; ++j) { s1 += subhist[t*10+j]; s2 += subhist[j*10+t]; }
        hxm[t] = (float)s1; hym[t] = (float)s2;
    }
    __syncthreads();
    {
        float term = 0.0f;
        if (t < 100) {
            const float denom = 8388608.0f, eps = 1e-8f;
            float pxy = (float)subhist[t] / denom;
            float px = hxm[t / 10] / denom, py = hym[t % 10] / denom;
            term = pxy * logf((pxy + eps) / (px * py + eps));
        }
        if (t < 128) mterm[t] = (t < 100) ? term : 0.0f;
    }
    __syncthreads();
    if (t == 0) {
        const float denom = 8388608.0f, eps = 1e-8f;
        float mi = 0.0f;
        for (int q = 0; q < 100; ++q) mi += mterm[q];
        float hxe = 0.0f, hye = 0.0f;
        for (int q = 0; q < 10; ++q) {
            float px = hxm[q] / denom, py = hym[q] / denom;
            hxe -= px * logf(px + eps);
            hye -= py * logf(py + eps);
        }
        wnmi[row] = mi / (0.5f * (hxe + hye));
    }
    // no barrier needed: stage 2 below ends with one; t==0 just arrives late

    // ---- FFT1 remaining forward stages: natural -> s-order
    stage_dif8<-1,  8>(sz, t);   // Q=256
    stage_dif8<-1,  5>(sz, t);   // Q=32
    stage_dif8<-1,  2>(sz, t);   // Q=4
    stage_nt4<-1>(sz, t);        // Q=1, twiddle-free

    // ---- Fused unpack: power sums (unwindowed) + phase-correlation C from
    //      the Hann-convolved spectrum (Zw[k] = 0.5Z[k]-0.25(Z[k-1]+Z[k+1]),
    //      exact for the periodic window). Reads before barrier; C written
    //      to NATURAL slots [0..8192] after (spectrum is dead by then).
    {
        double anum = 0.0, aden = 0.0;
        float crv[8], civ[8];
        #pragma unroll 1
        for (int m = 0; m < 8; ++m) {
            int k = t + (m << 10);
            int km = (SS - k) & (SS - 1);
            float2 za = sz[sp(k)];
            float2 zb = sz[sp(km)];
            float ar  = za.x, ai  = za.y;
            float cr0 = zb.x, ci0 = zb.y;
            float xr = 0.5f * (ar + cr0), xi = 0.5f * (ai - ci0);
            float yr = 0.5f * (ai + ci0), yi = 0.5f * (cr0 - ar);
            float xp = xr * xr + xi * xi;
            float tp = yr * yr + yi * yi;
            anum += (double)fabsf(xp - tp);
            aden += (double)tp;
            float2 zap = sz[sp((k + 1) & (SS - 1))];
            float2 zam = sz[sp((k - 1) & (SS - 1))];
            float2 zbp = sz[sp((km + 1) & (SS - 1))];
            float2 zbm = sz[sp((km - 1) & (SS - 1))];
            float zwr = 0.5f * ar  - 0.25f * (zap.x + zam.x);
            float zwi = 0.5f * ai  - 0.25f * (zap.y + zam.y);
            float vwr = 0.5f * cr0 - 0.25f * (zbp.x + zbm.x);
            float vwi = 0.5f * ci0 - 0.25f * (zbp.y + zbm.y);
            float xwr = 0.5f * (zwr + vwr), xwi = 0.5f * (zwi - vwi);
            float ywr = 0.5f * (zwi + vwi), ywi = 0.5f * (vwr - zwr);
            float cr = xwr * ywr + xwi * ywi;
            float ci = xwi * ywr - xwr * ywi;
            float mag = sqrtf(cr * cr + ci * ci);
            crv[m] = cr / mag; civ[m] = ci / mag;
        }
        float c8 = 0.0f;
        if (t == 0) {   // k = 8192 (self-conjugate)
            float2 z0 = sz[sp(8192)];
            float2 zp = sz[sp(8193)];
            float2 zm = sz[sp(8191)];
            float ar = z0.x, ai = z0.y;
            anum += (double)fabsf(ar * ar - ai * ai);
            aden += (double)(ai * ai);
            float zwr = 0.5f * ar - 0.25f * (zp.x + zm.x);
            float zwi = 0.5f * ai - 0.25f * (zp.y + zm.y);
            float pr = zwr * zwi;          // Xw real, Yw real at Nyquist
            c8 = pr / fabsf(pr);
        }
        #pragma unroll
        for (int o = 32; o > 0; o >>= 1) {
            anum += __shfl_down(anum, o, 64);
            aden += __shfl_down(aden, o, 64);
        }
        if (lane == 0) { dpart[w*2] = anum; dpart[w*2+1] = aden; }
        __syncthreads();   // all spectrum reads done; safe to overwrite
        #pragma unroll
        for (int m = 0; m < 8; ++m) {
            int k = t + (m << 10);
            sz[k] = make_float2(crv[m], civ[m]);   // C natural, k in [0,8192)
        }
        if (t == 0) {
            sz[8192] = make_float2(c8, 0.0f);
            double a = 0, b = 0;
            for (int q2_ = 0; q2_ < 16; ++q2_) { a += dpart[q2_*2]; b += dpart[q2_*2+1]; }
            wnum[row] = a; wden[row] = b;
        }
    }
    __syncthreads();

    // ---- 8K inverse: fused B-build+first stage, middle stages, fused last
    inv_first(sz, bz, t);         // B in regs + Q=1024 (barrier inside)
    stage8k_dif8<1,  7>(bz, t);   // Q=128
    stage8k_dif8<1,  4>(bz, t);   // Q=16
    stage8k_dif4<1>(bz, t);       // Q=4
    {
        float bv; int bi;
        inv_last_argmax(bz, t, &bv, &bi);   // Q=1 butterfly + argmax, no store
        #pragma unroll
        for (int o = 32; o > 0; o >>= 1) {
            float v2 = __shfl_down(bv, o, 64);
            int i2 = __shfl_down(bi, o, 64);
            if (v2 > bv || (v2 == bv && i2 < bi)) { bv = v2; bi = i2; }
        }
        if (lane == 0) { svalw[w] = bv; sidxw[w] = bi; }
    }
    __syncthreads();
    if (t == 0) {
        float bv = svalw[0]; int bi = sidxw[0];
        for (int q = 1; q < 16; ++q) {
            if (svalw[q] > bv || (svalw[q] == bv && sidxw[q] < bi)) { bv = svalw[q]; bi = sidxw[q]; }
        }
        wcos[row] = cosf(TPIF * (float)bi / 16384.0f);
    }
}

// ---------------------------------------------------------------------------
// Final combine (reads epoch on-device; graph-safe). Wave-shuffle reductions.
// ---------------------------------------------------------------------------
__global__ __launch_bounds__(512) void k_combine(const float* __restrict__ wpear,
                                                 const float* __restrict__ wcos,
                                                 const double* __restrict__ wnum,
                                                 const double* __restrict__ wden,
                                                 const float* __restrict__ wnmi,
                                                 const int* __restrict__ ep,
                                                 float* __restrict__ out) {
    __shared__ double dp[8 * 5];
    const int tid = threadIdx.x;
    const int w = tid >> 6, lane = tid & 63;
    double v0 = (double)wpear[tid], v1 = (double)wcos[tid];
    double v2 = wnum[tid], v3 = wden[tid], v4 = (double)wnmi[tid];
    #pragma unroll
    for (int o = 32; o > 0; o >>= 1) {
        v0 += __shfl_down(v0, o, 64); v1 += __shfl_down(v1, o, 64);
        v2 += __shfl_down(v2, o, 64); v3 += __shfl_down(v3, o, 64);
        v4 += __shfl_down(v4, o, 64);
    }
    if (lane == 0) {
        dp[w*5+0] = v0; dp[w*5+1] = v1; dp[w*5+2] = v2; dp[w*5+3] = v3; dp[w*5+4] = v4;
    }
    __syncthreads();
    if (tid == 0) {
        double s0=0,s1=0,s2=0,s3=0,s4=0;
        for (int q = 0; q < 8; ++q) {
            s0 += dp[q*5]; s1 += dp[q*5+1]; s2 += dp[q*5+2]; s3 += dp[q*5+3]; s4 += dp[q*5+4];
        }
        int epoch = ep[0];
        double loss = s0 / 512.0;
        if (epoch >= 400) {
            loss += 1.0 - s1 / 512.0;
            loss += s2 / s3;
        }
        if (epoch >= 700) {
            loss += 1.0 - s4 / 512.0;
        }
        out[0] = (float)loss;
    }
}

// ---------------------------------------------------------------------------
extern "C" void kernel_launch(void* const* d_in, const int* in_sizes, int n_in,
                              void* d_out, int out_size, void* d_ws, size_t ws_size,
                              hipStream_t stream) {
    const float* pred = (const float*)d_in[0];   // [2, 512, 16384] f32
    const float* targ = (const float*)d_in[1];   // [512, 16384] f32
    const int* ip = (const int*)d_in[2];         // scalar i
    const int* ep = (const int*)d_in[3];         // scalar epoch
    float* out = (float*)d_out;

    double* wnum = (double*)d_ws;                // [512]
    double* wden = wnum + BB;                    // [512]
    float* wpear = (float*)(wden + BB);          // [512]
    float* wcos = wpear + BB;                    // [512]
    float* wnmi = wcos + BB;                     // [512]

    k_main<<<dim3(BB), dim3(1024), 0, stream>>>(pred, targ, ip, wpear, wcos, wnum, wden, wnmi);
    k_combine<<<dim3(1), dim3(512), 0, stream>>>(wpear, wcos, wnum, wden, wnmi, ep, out);
}